// Round 15
// baseline (509.320 us; speedup 1.0000x reference)
//
#include <hip/hip_runtime.h>
#include <hip/hip_bf16.h>

// ---- problem constants ----
#define BSZ  32
#define CTX  8192
#define NP_  512
#define PSZ  16
#define DM_  1024
#define DS_  16
#define DI_  2048
#define DTR_ 64
#define NTOK (BSZ*NP_)   // 16384

typedef __hip_bfloat16 bf16;
typedef short bf16x8 __attribute__((ext_vector_type(8)));
typedef float f32x4  __attribute__((ext_vector_type(4)));

typedef __attribute__((address_space(3))) void lds_t;
typedef __attribute__((address_space(1))) void gbl_t;

__device__ inline float bf2f(bf16 v){ return __bfloat162float(v); }
__device__ inline bf16  f2bf(float v){ return __float2bfloat16(v); }
__device__ inline float bfs2f(short s){ union{unsigned u; float f;} x; x.u = ((unsigned)(unsigned short)s)<<16; return x.f; }
__device__ inline short f2bfs(float v){ bf16 b = f2bf(v); return *reinterpret_cast<short*>(&b); }
__device__ inline float fast_sigmoid(float x){ return 1.0f/(1.0f+__expf(-x)); }
__device__ inline void stout(float* p, float v){ *p = v; }
__device__ inline void stout(bf16* p, float v){ *p = f2bf(v); }
// hardware 2^x / log2 (single-inst); libm exp2f/log1pf are the slow precise paths
__device__ inline float hw_exp2(float x){ float r; asm("v_exp_f32 %0, %1" : "=v"(r) : "v"(x)); return r; }
__device__ inline float hw_log2(float x){ float r; asm("v_log_f32 %0, %1" : "=v"(r) : "v"(x)); return r; }
__device__ inline float softplus_fast(float x){
  if (x > 15.0f) return x;
  return 0.69314718f * hw_log2(1.0f + hw_exp2(x * 1.44269504f));
}

__device__ inline void gload_lds16(const void* g, void* l){
  __builtin_amdgcn_global_load_lds((const gbl_t*)g, (lds_t*)l, 16, 0, 0);
}

// ---- transpose+cvt body: T[n][k] = W[k][col0+n] (n<nvalid else 0), 64x64 tile ----
__device__ inline void transpose_cvt_body(
    int bx, int by, const float* __restrict__ W, bf16* __restrict__ T,
    int ldw, int col0, int nvalid, int K, int tid, float (*tile)[65])
{
  int kb = bx << 6, nb = by << 6;
  int c = tid & 63, r4 = tid >> 6;
  #pragma unroll
  for (int i=0;i<16;i++){
    int r = r4 + i*4;
    int kk = kb + r, nn = nb + c;
    float v = 0.f;
    if (kk < K && nn < nvalid) v = W[(size_t)kk*ldw + col0 + nn];
    tile[r][c] = v;
  }
  __syncthreads();
  #pragma unroll
  for (int i=0;i<16;i++){
    int r = r4 + i*4;
    T[(size_t)(nb + r)*K + kb + c] = f2bf(tile[c][r]);
  }
}

// ---- merged prep: winT transpose | wxT | wdtT | posemb | cwT ----
__global__ __launch_bounds__(256) void k_prep_all(
    const float* __restrict__ W_in, bf16* __restrict__ winT,
    const float* __restrict__ W_x,  bf16* __restrict__ wxT,
    const float* __restrict__ W_dt, bf16* __restrict__ wdtT,
    float* __restrict__ pe,
    const float* __restrict__ cw, float* __restrict__ cwT)
{
  __shared__ float tile[64][65];
  int b = blockIdx.x, tid = threadIdx.x;
  if (b < 1024){
    transpose_cvt_body(b & 15, b >> 4, W_in, winT, 4096, 0, 4096, 1024, tid, tile);
  } else if (b < 1088){
    int t = b - 1024;
    transpose_cvt_body(t & 31, t >> 5, W_x, wxT, 96, 0, 96, 2048, tid, tile);
  } else if (b < 1120){
    int t = b - 1088;
    transpose_cvt_body(0, t, W_dt, wdtT, 2048, 0, 2048, 64, tid, tile);
  } else if (b < 3168){
    int idx = (b - 1120)*256 + tid;        // 512*1024 sincos table
    int n = idx >> 10, c = idx & 1023;
    int j2 = c & 511;
    float omega = exp2f(-13.2877123795495f * ((float)j2 * (1.0f/511.0f)));
    float ang = (float)n * omega;
    pe[idx] = (c < 512) ? sinf(ang) : cosf(ang);
  } else {
    int idx = (b - 3168)*256 + tid;        // 4*2048 conv-weight transpose
    int k = idx >> 11, d = idx & 2047;
    cwT[idx] = cw[d*4 + k];
  }
}

// ---- patch embedding: 16 tokens/block, Wp columns cached in registers ----
__global__ __launch_bounds__(256) void k_patch(
    const float* __restrict__ x, const float* __restrict__ g1, const float* __restrict__ b1,
    const float* __restrict__ Wp, const float* __restrict__ bp,
    const float* __restrict__ g2, const float* __restrict__ b2,
    const float* __restrict__ pe, bf16* __restrict__ h)
{
  __shared__ float pns[2][16];
  __shared__ float red[8];
  int tid = threadIdx.x;
  int w = tid >> 6, l = tid & 63;
  int tok0 = blockIdx.x << 4;         // 1024 blocks x 16 tokens (batch-aligned: 16|512)
  int bb = tok0 >> 9, n0 = tok0 & 511;
  float wreg[4][16];
  #pragma unroll
  for (int q=0;q<4;q++)
    #pragma unroll
    for (int i=0;i<16;i++)
      wreg[q][i] = Wp[i*1024 + tid + q*256];
  float bpv[4], g2v[4], b2v[4];
  #pragma unroll
  for (int q=0;q<4;q++){
    int j = tid + q*256;
    bpv[q] = bp[j]; g2v[q] = g2[j]; b2v[q] = b2[j];
  }
  float g1v = 0.f, b1v = 0.f;
  if (tid < 16){ g1v = g1[tid]; b1v = b1[tid]; }
  for (int tt=0; tt<16; ++tt){
    int buf = tt & 1;
    if (tid < 16){
      float v = x[(size_t)bb*CTX + (n0+tt)*16 + tid];
      float m = v;
      #pragma unroll
      for (int o=1;o<16;o<<=1) m += __shfl_xor(m, o, 64);
      m *= (1.0f/16.0f);
      float dv = v - m;
      float s = dv*dv;
      #pragma unroll
      for (int o=1;o<16;o<<=1) s += __shfl_xor(s, o, 64);
      float rs = rsqrtf(s*(1.0f/16.0f) + 1e-5f);
      pns[buf][tid] = dv*rs*g1v + b1v;
    }
    __syncthreads();
    float acc[4];
    #pragma unroll
    for (int q=0;q<4;q++) acc[q] = bpv[q];
    #pragma unroll
    for (int i=0;i<16;i++){
      float p = pns[buf][i];
      #pragma unroll
      for (int q=0;q<4;q++) acc[q] += p*wreg[q][i];
    }
    float s1 = acc[0]+acc[1]+acc[2]+acc[3];
    float s2 = acc[0]*acc[0]+acc[1]*acc[1]+acc[2]*acc[2]+acc[3]*acc[3];
    #pragma unroll
    for (int o=32;o;o>>=1){ s1 += __shfl_down(s1,o,64); s2 += __shfl_down(s2,o,64); }
    if (l==0){ red[w]=s1; red[4+w]=s2; }
    __syncthreads();
    float mu  = (red[0]+red[1]+red[2]+red[3])*(1.0f/1024.0f);
    float var = (red[4]+red[5]+red[6]+red[7])*(1.0f/1024.0f) - mu*mu;
    float rs2 = rsqrtf(var + 1e-5f);
    size_t tok = (size_t)(tok0 + tt);
    #pragma unroll
    for (int q=0;q<4;q++){
      int j = tid + q*256;
      float val = (acc[q]-mu)*rs2*g2v[q] + b2v[q] + pe[(n0+tt)*1024 + j];
      h[tok*1024 + j] = f2bf(val);
    }
  }
}

// ==== 256x256-tile 8-wave in_proj GEMM, counted-vmcnt double-buffer (T3+T4), ====
// ==== T2 swizzle, T5 setprio; B-fragments hoisted per kk.                     ====
__global__ __launch_bounds__(512, 2) void k_gemm256(
    const bf16* __restrict__ A, const bf16* __restrict__ BT,
    bf16* __restrict__ Cu, bf16* __restrict__ Cz, int M, int N, int K)
{
  __shared__ __align__(16) bf16 As[2][256*64];
  __shared__ __align__(16) bf16 Bs[2][256*64];
  const int tid = threadIdx.x;
  const int w = tid >> 6, l = tid & 63, lr = l & 15, lg = l >> 4;
  const int wm = w >> 2, wn = w & 3;
  int nblk = N >> 8;
  int nwg = gridDim.x;
  int wg  = (blockIdx.x & 7) * (nwg >> 3) + (blockIdx.x >> 3);
  const int GM = 4;
  int band = GM * nblk;
  int grp = wg / band, loc = wg % band;
  int bm = grp*GM + (loc % GM);
  int bn = loc / GM;
  int m0 = bm << 8, n0 = bn << 8;

  f32x4 acc[8][4] = {};

  int rowS[4], colS[4];
  #pragma unroll
  for (int j=0;j<4;j++){
    int bo = (j*8 + w)*1024 + l*16;
    int r = bo >> 7;
    int c = (bo & 127) ^ ((r & 7) << 4);
    rowS[j] = r; colS[j] = c >> 1;
  }
  const bf16* Ag = A  + (size_t)m0 * K;
  const bf16* Bg = BT + (size_t)n0 * K;

  #define STAGE(buf, kt) do {                                                   \
    _Pragma("unroll")                                                           \
    for (int j=0;j<4;j++)                                                       \
      gload_lds16(Ag + (size_t)rowS[j]*K + (kt) + colS[j], &As[buf][(j*8+w)*512]); \
    _Pragma("unroll")                                                           \
    for (int j=0;j<4;j++)                                                       \
      gload_lds16(Bg + (size_t)rowS[j]*K + (kt) + colS[j], &Bs[buf][(j*8+w)*512]); \
  } while(0)

  int cswz[2];
  cswz[0] = (lg*8) ^ ((lr&7)<<3);
  cswz[1] = (32 + lg*8) ^ ((lr&7)<<3);
  const int rbA = (wm*128 + lr) * 64;
  const int rbB = (wn*64  + lr) * 64;

  #define COMPUTE(buf) do {                                                     \
    _Pragma("unroll")                                                           \
    for (int kk=0;kk<2;kk++){                                                   \
      bf16x8 bq[4];                                                             \
      _Pragma("unroll")                                                         \
      for (int j=0;j<4;j++) bq[j] = *(const bf16x8*)&Bs[buf][rbB + j*1024 + cswz[kk]]; \
      _Pragma("unroll")                                                         \
      for (int rh=0;rh<2;rh++){                                                 \
        bf16x8 af[4];                                                           \
        _Pragma("unroll")                                                       \
        for (int i=0;i<4;i++) af[i] = *(const bf16x8*)&As[buf][rbA + (rh*4+i)*1024 + cswz[kk]]; \
        __builtin_amdgcn_s_setprio(1);                                          \
        _Pragma("unroll")                                                       \
        for (int i=0;i<4;i++)                                                   \
          _Pragma("unroll")                                                     \
          for (int j=0;j<4;j++)                                                 \
            acc[rh*4+i][j] = __builtin_amdgcn_mfma_f32_16x16x32_bf16(af[i], bq[j], acc[rh*4+i][j], 0,0,0); \
        __builtin_amdgcn_s_setprio(0);                                          \
      }                                                                         \
    }                                                                           \
  } while(0)

  STAGE(0, 0);
  STAGE(1, 64);
  const int NT2 = K >> 7;
  int kt = 0;
  for (int t=0; t<NT2; ++t){
    const bool last = (t == NT2-1);
    asm volatile("s_waitcnt vmcnt(8)" ::: "memory");
    __builtin_amdgcn_sched_barrier(0);
    asm volatile("s_barrier" ::: "memory");
    COMPUTE(0);
    asm volatile("s_barrier" ::: "memory");
    __builtin_amdgcn_sched_barrier(0);
    if (!last) STAGE(0, kt + 128);
    if (!last) { asm volatile("s_waitcnt vmcnt(8)" ::: "memory"); }
    else       { asm volatile("s_waitcnt vmcnt(0)" ::: "memory"); }
    __builtin_amdgcn_sched_barrier(0);
    asm volatile("s_barrier" ::: "memory");
    COMPUTE(1);
    if (!last){
      asm volatile("s_barrier" ::: "memory");
      __builtin_amdgcn_sched_barrier(0);
      STAGE(1, kt + 192);
    }
    kt += 128;
  }
  #undef STAGE
  #undef COMPUTE

  #pragma unroll
  for (int fr=0;fr<8;fr++)
    #pragma unroll
    for (int fc=0;fc<4;fc++)
      #pragma unroll
      for (int rr=0;rr<4;rr++){
        int row  = m0 + wm*128 + fr*16 + lg*4 + rr;
        int gcol = n0 + wn*64 + fc*16 + lr;
        float v = acc[fr][fc][rr];
        if (gcol < 2048) Cu[(size_t)row*2048 + gcol] = f2bf(v);
        else { v = v * fast_sigmoid(v); Cz[(size_t)row*2048 + gcol - 2048] = f2bf(v); }
      }
}

// ---- bf16 MFMA GEMM (legacy 128^2 BK=32): used for dt-GEMM (EPI=1) ----
template<int EPI, typename OT>
__global__ __launch_bounds__(256) void k_gemm_bt(
    const bf16* __restrict__ A, const bf16* __restrict__ BT, OT* __restrict__ C,
    bf16* __restrict__ C2, int M, int N, int K, const float* __restrict__ bias)
{
  __shared__ __align__(16) bf16 As[128*32];
  __shared__ __align__(16) bf16 Bs[128*32];
  int tid = threadIdx.x;
  int mblk = M >> 7, nblk = N >> 7;
  int nwg = gridDim.x;
  int wg  = (blockIdx.x & 7) * (nwg >> 3) + (blockIdx.x >> 3);
  const int GM = 8;
  int band = GM * nblk;
  int grp = wg / band, loc = wg % band;
  int bm = grp*GM + (loc % GM);
  int bn = loc / GM;
  int m0 = bm << 7, n0 = bn << 7;
  int w = tid >> 6, l = tid & 63, lr = l & 15, lg = l >> 4;
  int wm = w >> 1, wn = w & 1;
  f32x4 acc[4][4] = {};
  int r0 = tid >> 2, c0 = (tid & 3) << 3;
  const bf16* Asrc = A  + (size_t)(m0 + r0) * K + c0;
  const bf16* Bsrc = BT + (size_t)(n0 + r0) * K + c0;
  bf16* AsW = As + w*512;
  bf16* BsW = Bs + w*512;
  for (int kt = 0; kt < K; kt += 32){
    __syncthreads();
    gload_lds16(Asrc + kt,                   AsW);
    gload_lds16(Asrc + (size_t)64*K + kt,    AsW + 2048);
    gload_lds16(Bsrc + kt,                   BsW);
    gload_lds16(Bsrc + (size_t)64*K + kt,    BsW + 2048);
    __syncthreads();
    bf16x8 af[4], bfr[4];
    #pragma unroll
    for (int i=0;i<4;i++) af[i]  = *(const bf16x8*)(As + (wm*64 + i*16 + lr)*32 + lg*8);
    #pragma unroll
    for (int j=0;j<4;j++) bfr[j] = *(const bf16x8*)(Bs + (wn*64 + j*16 + lr)*32 + lg*8);
    #pragma unroll
    for (int i=0;i<4;i++)
      #pragma unroll
      for (int j=0;j<4;j++)
        acc[i][j] = __builtin_amdgcn_mfma_f32_16x16x32_bf16(af[i], bfr[j], acc[i][j], 0,0,0);
  }
  #pragma unroll
  for (int i=0;i<4;i++)
    #pragma unroll
    for (int j=0;j<4;j++)
      #pragma unroll
      for (int r=0;r<4;r++){
        int row = m0 + wm*64 + i*16 + lg*4 + r;
        int col = wn*64 + j*16 + lr;
        int gcol = n0 + col;
        float v = acc[i][j][r];
        if (EPI == 0) stout(&C[(size_t)row*N + gcol], v);
        if (EPI == 1){ v = softplus_fast(v + bias[gcol]); stout(&C[(size_t)row*N + gcol], v); }
      }
}

// ---- x_proj split-K x4 GEMM (BK=32): chunk c covers K in [c*512, c*512+512) ----
__global__ __launch_bounds__(256) void k_gemm_xk(
    const bf16* __restrict__ A, const bf16* __restrict__ BT,
    float* __restrict__ C0, float* __restrict__ C1,
    float* __restrict__ C2, float* __restrict__ C3)
{
  __shared__ __align__(16) bf16 As[128*32];
  __shared__ __align__(16) bf16 Bs[128*32];
  int tid = threadIdx.x;
  int nwg = gridDim.x;
  int wg  = (blockIdx.x & 7) * (nwg >> 3) + (blockIdx.x >> 3);
  int chunk = wg >> 7;
  int bm = wg & 127;
  int m0 = bm << 7;
  int kbase = chunk << 9;
  int w = tid >> 6, l = tid & 63, lr = l & 15, lg = l >> 4;
  int wm = w >> 1, wn = w & 1;
  f32x4 acc[4][4] = {};
  int r0 = tid >> 2, c0 = (tid & 3) << 3;
  const bf16* Asrc = A  + (size_t)(m0 + r0) * 2048 + kbase + c0;
  const bf16* Bsrc = BT + (size_t)r0 * 2048 + kbase + c0;
  bf16* AsW = As + w*512;
  bf16* BsW = Bs + w*512;
  float* Cp = (chunk==0) ? C0 : (chunk==1) ? C1 : (chunk==2) ? C2 : C3;
  for (int kt = 0; kt < 512; kt += 32){
    __syncthreads();
    gload_lds16(Asrc + kt,                      AsW);
    gload_lds16(Asrc + (size_t)64*2048 + kt,    AsW + 2048);
    gload_lds16(Bsrc + kt,                      BsW);
    gload_lds16(Bsrc + (size_t)64*2048 + kt,    BsW + 2048);
    __syncthreads();
    bf16x8 af[4], bfr[4];
    #pragma unroll
    for (int i=0;i<4;i++) af[i]  = *(const bf16x8*)(As + (wm*64 + i*16 + lr)*32 + lg*8);
    #pragma unroll
    for (int j=0;j<4;j++) bfr[j] = *(const bf16x8*)(Bs + (wn*64 + j*16 + lr)*32 + lg*8);
    #pragma unroll
    for (int i=0;i<4;i++)
      #pragma unroll
      for (int j=0;j<4;j++)
        acc[i][j] = __builtin_amdgcn_mfma_f32_16x16x32_bf16(af[i], bfr[j], acc[i][j], 0,0,0);
  }
  #pragma unroll
  for (int i=0;i<4;i++)
    #pragma unroll
    for (int j=0;j<4;j++)
      #pragma unroll
      for (int r=0;r<4;r++){
        int row = m0 + wm*64 + i*16 + lg*4 + r;
        int gcol = wn*64 + j*16 + lr;
        Cp[(size_t)row*128 + gcol] = acc[i][j][r];
      }
}

// ---- x_proj fixup: xd = p0+p1+p2+p3 (in place into xd); dt = bf16(xd[:, :64]) ----
__global__ __launch_bounds__(256) void k_xproj_fix(
    float* __restrict__ xd, const float* __restrict__ p1,
    const float* __restrict__ p2, const float* __restrict__ p3,
    bf16* __restrict__ dt)
{
  int idx = blockIdx.x*256 + threadIdx.x;   // 16384*128
  int row = idx >> 7, col = idx & 127;
  float v = xd[idx] + p1[idx] + p2[idx] + p3[idx];
  xd[idx] = v;
  if (col < 64) dt[(row << 6) + col] = f2bf(v);
}

// ---- causal depthwise conv (DC=4) + SiLU, sliding-window vectorized ----
__global__ __launch_bounds__(256) void k_conv(
    const bf16* __restrict__ u, const float* __restrict__ cwT, const float* __restrict__ cb,
    bf16* __restrict__ uc)
{
  int tid = threadIdx.x;
  int d = tid << 3;
  int tok0 = blockIdx.x << 4;       // 1024 blocks x 16 tokens
  int n0 = tok0 & 511;              // position within batch
  float wk[4][8];
  #pragma unroll
  for (int k=0;k<4;k++){
    *(float4*)&wk[k][0] = *(const float4*)(cwT + k*2048 + d);
    *(float4*)&wk[k][4] = *(const float4*)(cwT + k*2048 + d + 4);
  }
  float cbv[8];
  *(float4*)&cbv[0] = *(const float4*)(cb + d);
  *(float4*)&cbv[4] = *(const float4*)(cb + d + 4);
  bf16x8 w0, w1, w2;
  if (n0 == 0){
    w0 = (bf16x8){0,0,0,0,0,0,0,0}; w1 = w0; w2 = w0;
  } else {
    w0 = *(const bf16x8*)(u + (size_t)(tok0-3)*2048 + d);
    w1 = *(const bf16x8*)(u + (size_t)(tok0-2)*2048 + d);
    w2 = *(const bf16x8*)(u + (size_t)(tok0-1)*2048 + d);
  }
  #pragma unroll 4
  for (int t=0; t<16; ++t){
    size_t tok = (size_t)(tok0 + t);
    bf16x8 cur = *(const bf16x8*)(u + tok*2048 + d);
    bf16x8 res;
    #pragma unroll
    for (int j=0;j<8;j++){
      float a = cbv[j]
              + wk[0][j]*bfs2f(w0[j]) + wk[1][j]*bfs2f(w1[j])
              + wk[2][j]*bfs2f(w2[j]) + wk[3][j]*bfs2f(cur[j]);
      res[j] = f2bfs(a * fast_sigmoid(a));
    }
    *(bf16x8*)(uc + tok*2048 + d) = res;
    w0 = w1; w1 = w2; w2 = cur;
  }
}

// ---- selective scan, 2-half time-split (linear recurrence decomposition) ----
// grid 2048 = b(32) x half(2) x dgrp(32); 64 d/block, 4 lanes/d (r10 layout).
// half 0: t in [0,256), writes final state H[b,d,16] + partial acc.
// half 1: t in [256,512) from zero state; tracks propagator P and moment
//   M[n] = sum_t g_t*C_t[n]*P_t[n]; fix-up adds sum_n H[n]*M[n].
__global__ __launch_bounds__(256) void k_scan(
    const bf16* __restrict__ delta, const bf16* __restrict__ uc, const bf16* __restrict__ g,
    const float* __restrict__ xd, const float* __restrict__ A_log,
    const float* __restrict__ Dp, float* __restrict__ hmid,
    float* __restrict__ Mbuf, float* __restrict__ pacc)
{
  int tid = threadIdx.x;
  int q  = tid & 3;          // state quad
  int dl = tid >> 2;         // 64 d per block
  int bx = blockIdx.x;
  int b    = bx >> 6;
  int half = (bx >> 5) & 1;
  int d  = ((bx & 31) << 6) + dl;
  const float L2E = 1.44269504f;
  float4 t4 = *(const float4*)(A_log + (size_t)d*16 + q*4);
  float An0 = -__expf(t4.x)*L2E, An1 = -__expf(t4.y)*L2E,
        An2 = -__expf(t4.z)*L2E, An3 = -__expf(t4.w)*L2E;
  float Dd = (q == 0) ? Dp[d] : 0.0f;
  float h0=0.f,h1=0.f,h2=0.f,h3=0.f;
  float acc = 0.0f;
  unsigned o1 = (unsigned)b*1048576u + (unsigned)half*524288u + (unsigned)d;
  unsigned o2 = (unsigned)b*16384u + (unsigned)half*8192u + 16u + (unsigned)q;
  const float4* __restrict__ x4 = (const float4*)xd;
  size_t sidx = ((size_t)b*2048 + d)*16 + q*4;   // H / M slot for this lane
  if (half == 0){
    #pragma unroll 4
    for (int t=0; t<256; ++t){
      float dt = bf2f(delta[o1]);
      float ut = bf2f(uc[o1]);
      float gt = bf2f(g[o1]);
      float4 Bq = x4[o2];
      float4 Cq = x4[o2 + 4u];
      o1 += 2048u; o2 += 32u;
      float du = dt*ut;
      float y;
      float e0 = hw_exp2(dt*An0); h0 = h0*e0 + du*Bq.x; y  = h0*Cq.x;
      float e1 = hw_exp2(dt*An1); h1 = h1*e1 + du*Bq.y; y += h1*Cq.y;
      float e2 = hw_exp2(dt*An2); h2 = h2*e2 + du*Bq.z; y += h2*Cq.z;
      float e3 = hw_exp2(dt*An3); h3 = h3*e3 + du*Bq.w; y += h3*Cq.w;
      acc += (y + ut*Dd) * gt;
    }
    *(float4*)(hmid + sidx) = make_float4(h0, h1, h2, h3);
  } else {
    float P0=1.f,P1=1.f,P2=1.f,P3=1.f;
    float M0=0.f,M1=0.f,M2=0.f,M3=0.f;
    #pragma unroll 4
    for (int t=0; t<256; ++t){
      float dt = bf2f(delta[o1]);
      float ut = bf2f(uc[o1]);
      float gt = bf2f(g[o1]);
      float4 Bq = x4[o2];
      float4 Cq = x4[o2 + 4u];
      o1 += 2048u; o2 += 32u;
      float du = dt*ut;
      float y;
      float e0 = hw_exp2(dt*An0); h0 = h0*e0 + du*Bq.x; y  = h0*Cq.x; P0 *= e0; M0 = fmaf(gt, Cq.x*P0, M0);
      float e1 = hw_exp2(dt*An1); h1 = h1*e1 + du*Bq.y; y += h1*Cq.y; P1 *= e1; M1 = fmaf(gt, Cq.y*P1, M1);
      float e2 = hw_exp2(dt*An2); h2 = h2*e2 + du*Bq.z; y += h2*Cq.z; P2 *= e2; M2 = fmaf(gt, Cq.z*P2, M2);
      float e3 = hw_exp2(dt*An3); h3 = h3*e3 + du*Bq.w; y += h3*Cq.w; P3 *= e3; M3 = fmaf(gt, Cq.w*P3, M3);
      acc += (y + ut*Dd) * gt;
    }
    *(float4*)(Mbuf + sidx) = make_float4(M0, M1, M2, M3);
  }
  acc += __shfl_xor(acc, 1, 64);
  acc += __shfl_xor(acc, 2, 64);
  if (q == 0) pacc[(size_t)half*65536 + (size_t)b*2048 + d] = acc;
}

// ---- scan fix-up: ysum = acc0 + acc1 + sum_n H[n]*M[n] ----
__global__ __launch_bounds__(256) void k_scan_fix(
    const float* __restrict__ hmid, const float* __restrict__ Mbuf,
    const float* __restrict__ pacc, float* __restrict__ ysum)
{
  int idx = blockIdx.x*256 + threadIdx.x;   // 65536 = b*2048+d
  const float4* H = (const float4*)(hmid + (size_t)idx*16);
  const float4* M = (const float4*)(Mbuf + (size_t)idx*16);
  float c = 0.f;
  #pragma unroll
  for (int i=0;i<4;i++){
    float4 hh = H[i], mm = M[i];
    c += hh.x*mm.x + hh.y*mm.y + hh.z*mm.z + hh.w*mm.w;
  }
  ysum[idx] = pacc[idx] + pacc[65536 + idx] + c;
}

// ---- split-K pooled GEMM part 1 ----
__global__ __launch_bounds__(256) void k_poolgemm_part(
    const float* __restrict__ ysum, const float* __restrict__ Wo, float* __restrict__ partial)
{
  __shared__ float ys[32][64];
  int tid = threadIdx.x;
  int jb = blockIdx.x & 15;
  int kc = blockIdx.x >> 4;
  int j  = jb*64 + (tid & 63);
  int b0 = tid >> 6;
  #pragma unroll
  for (int i=0;i<8;i++){
    int e = tid + i*256;
    int bb = e >> 6, kk = e & 63;
    ys[bb][kk] = ysum[(size_t)bb*2048 + kc*64 + kk];
  }
  __syncthreads();
  float acc[8];
  #pragma unroll
  for (int p=0;p<8;p++) acc[p] = 0.f;
  #pragma unroll 4
  for (int kk=0;kk<64;kk++){
    float wv = Wo[(size_t)(kc*64 + kk)*1024 + j];
    #pragma unroll
    for (int p=0;p<8;p++) acc[p] += ys[b0*8 + p][kk] * wv;
  }
  #pragma unroll
  for (int p=0;p<8;p++)
    partial[((size_t)kc*32 + b0*8 + p)*1024 + j] = acc[p];
}

// ---- split-K pooled GEMM part 2 ----
__global__ __launch_bounds__(256) void k_pool_reduce(
    const float* __restrict__ partial, float* __restrict__ pooled)
{
  int idx = blockIdx.x*256 + threadIdx.x;    // 32768
  float s = 0.f;
  #pragma unroll 8
  for (int kc=0;kc<32;kc++) s += partial[(size_t)kc*32768 + idx];
  pooled[idx] = s * (1.0f/512.0f);
}

// ---- head: LN(1024) -> dot Wh + bh ----
__global__ __launch_bounds__(256) void k_head(
    const float* __restrict__ pooled, const float* __restrict__ g, const float* __restrict__ bb,
    const float* __restrict__ Wh, const float* __restrict__ bh, float* __restrict__ out)
{
  __shared__ float red[8];
  int b = blockIdx.x, tid = threadIdx.x;
  float v[4];
  #pragma unroll
  for (int q=0;q<4;q++) v[q] = pooled[(size_t)b*1024 + tid + q*256];
  float s1 = v[0]+v[1]+v[2]+v[3];
  float s2 = v[0]*v[0]+v[1]*v[1]+v[2]*v[2]+v[3]*v[3];
  #pragma unroll
  for (int o=32;o;o>>=1){ s1 += __shfl_down(s1,o,64); s2 += __shfl_down(s2,o,64); }
  int w = tid>>6, l = tid&63;
  if (l==0){ red[w]=s1; red[4+w]=s2; }
  __syncthreads();
  float mu  = (red[0]+red[1]+red[2]+red[3])*(1.0f/1024.0f);
  float var = (red[4]+red[5]+red[6]+red[7])*(1.0f/1024.0f) - mu*mu;
  float rs = rsqrtf(var + 1e-5f);
  float p = 0.f;
  #pragma unroll
  for (int q=0;q<4;q++){
    int jv = tid + q*256;
    p += ((v[q]-mu)*rs*g[jv] + bb[jv]) * Wh[jv];
  }
  #pragma unroll
  for (int o=32;o;o>>=1) p += __shfl_down(p,o,64);
  __syncthreads();
  if (l==0) red[w] = p;
  __syncthreads();
  if (tid==0) out[b] = red[0]+red[1]+red[2]+red[3] + bh[0];
}

extern "C" void kernel_launch(void* const* d_in, const int* in_sizes, int n_in,
                              void* d_out, int out_size, void* d_ws, size_t ws_size,
                              hipStream_t stream)
{
  const float* x     = (const float*)d_in[0];
  const float* ln1_g = (const float*)d_in[1];
  const float* ln1_b = (const float*)d_in[2];
  const float* Wp    = (const float*)d_in[3];
  const float* bp    = (const float*)d_in[4];
  const float* ln2_g = (const float*)d_in[5];
  const float* ln2_b = (const float*)d_in[6];
  const float* W_in  = (const float*)d_in[7];
  const float* conv_w= (const float*)d_in[8];
  const float* conv_b= (const float*)d_in[9];
  const float* W_x   = (const float*)d_in[10];
  const float* W_dt  = (const float*)d_in[11];
  const float* b_dt  = (const float*)d_in[12];
  const float* A_log = (const float*)d_in[13];
  const float* Dv    = (const float*)d_in[14];
  const float* W_out = (const float*)d_in[15];
  const float* ln3_g = (const float*)d_in[16];
  const float* ln3_b = (const float*)d_in[17];
  const float* Wh    = (const float*)d_in[18];
  const float* bh    = (const float*)d_in[19];

  // ---- workspace layout with liveness-based aliasing; peak ~234.8 MiB ----
  char* ws = (char*)d_ws;
  size_t o = 0;
  bf16*  u_delta = (bf16*)(ws + o); o += (size_t)NTOK*DI_*2;   // 64 MiB: u, then xpart2/3, then delta
  bf16*  zbuf    = (bf16*)(ws + o); o += (size_t)NTOK*DI_*2;   // 64 MiB: g = silu(z)
  bf16*  ucbuf   = (bf16*)(ws + o); o += (size_t)NTOK*DI_*2;   // 64 MiB: uc (persistent)
  char*  poolA   = (ws + o);        o += (size_t)NTOK*DM_*2;   // 32 MiB: h, later xd/dt/...
  bf16*  winT    = (bf16*)(ws + o); o += (size_t)2*DI_*DM_*2;  //  8 MiB: in_proj^T; later xpart1
  float* pe      = (float*)(ws + o); o += (size_t)NP_*DM_*4;   //  2 MiB
  bf16*  wxT     = (bf16*)(ws + o); o += (size_t)128*2048*2;   //  0.5 MiB (dedicated; no alias)
  bf16*  wdtT    = (bf16*)(ws + o); o += (size_t)2048*64*2;    //  0.25 MiB
  float* cwT     = (float*)(ws + o); o += (size_t)4*2048*4;    //  32 KiB
  bf16*  hbuf    = (bf16*)poolA;                 // phase-1
  float* xdbuf   = (float*)(poolA + 0);          // 8.0 MiB  [16384,128] f32
  bf16*  dtbuf   = (bf16*) (poolA + 8388608);    // 2.0 MiB  [16384,64]
  float* ysumbuf = (float*)(poolA + 11272192);   // 0.25 MiB [32,2048]
  float* pooledb = (float*)(poolA + 11534336);   // 0.13 MiB [32,1024]
  float* partial = (float*)(poolA + 12582912);   // 4.0 MiB  [32,32,1024]
  float* hmid    = (float*)(poolA + 16777216);   // 4.0 MiB  [32,2048,16] f32
  float* Mbuf    = (float*)(poolA + 20971520);   // 4.0 MiB  [32,2048,16] f32
  float* paccb   = (float*)(poolA + 25165824);   // 0.5 MiB  [2,32,2048] f32
  float* xpart1  = (float*)winT;                 // 8.0 MiB  (winT dead after gemm256)
  float* xpart2  = (float*)u_delta;              // 8.0 MiB  (u dead after conv)
  float* xpart3  = (float*)((char*)u_delta + 8388608); // 8.0 MiB

  // all weight preps + posemb in one kernel (saves 4 launches)
  k_prep_all      <<<3200, 256, 0, stream>>>(W_in, winT, W_x, wxT, W_dt, wdtT, pe, conv_w, cwT);
  k_patch         <<<1024, 256, 0, stream>>>(x, ln1_g, ln1_b, Wp, bp, ln2_g, ln2_b, pe, hbuf);
  // merged in_proj via 256^2 8-wave counted-vmcnt kernel
  k_gemm256       <<<1024, 512, 0, stream>>>(hbuf, winT, u_delta, zbuf, NTOK, 4096, 1024);
  // conv(u) -> uc   (hbuf + u dead from here)
  k_conv          <<<1024, 256, 0, stream>>>(u_delta, cwT, conv_b, ucbuf);
  // x_proj: split-K x4 (partials in dead winT + u_delta), then fixup emits xd + dt
  k_gemm_xk       <<<512,  256, 0, stream>>>(ucbuf, wxT, xdbuf, xpart1, xpart2, xpart3);
  k_xproj_fix     <<<8192, 256, 0, stream>>>(xdbuf, xpart1, xpart2, xpart3, dtbuf);
  // delta = softplus(dt @ W_dt + b_dt)  (overwrites u_delta; xparts dead)
  k_gemm_bt<1,bf16><<<2048,256, 0, stream>>>(dtbuf, wdtT, u_delta, nullptr, NTOK, 2048, 64, b_dt);
  // fused scan: 2-half time split (2048 blocks = 8 waves/SIMD), then fix-up
  k_scan          <<<2048, 256, 0, stream>>>(u_delta, ucbuf, zbuf, xdbuf, A_log, Dv, hmid, Mbuf, paccb);
  k_scan_fix      <<<256,  256, 0, stream>>>(hmid, Mbuf, paccb, ysumbuf);
  // pooled = (ysum/512) @ W_out : split-K over 512 blocks, then reduce
  k_poolgemm_part <<<512,  256, 0, stream>>>(ysumbuf, W_out, partial);
  k_pool_reduce   <<<128,  256, 0, stream>>>(partial, pooledb);
  k_head          <<<32,   256, 0, stream>>>(pooledb, ln3_g, ln3_b, Wh, bh, (float*)d_out);
  (void)in_sizes; (void)n_in; (void)out_size; (void)ws_size;
}

// Round 16
// 438.049 us; speedup vs baseline: 1.1627x; 1.1627x over previous
//
#include <hip/hip_runtime.h>
#include <hip/hip_bf16.h>

// ---- problem constants ----
#define BSZ  32
#define CTX  8192
#define NP_  512
#define PSZ  16
#define DM_  1024
#define DS_  16
#define DI_  2048
#define DTR_ 64
#define NTOK (BSZ*NP_)   // 16384

typedef __hip_bfloat16 bf16;
typedef short bf16x8 __attribute__((ext_vector_type(8)));
typedef float f32x4  __attribute__((ext_vector_type(4)));

typedef __attribute__((address_space(3))) void lds_t;
typedef __attribute__((address_space(1))) void gbl_t;

__device__ inline float bf2f(bf16 v){ return __bfloat162float(v); }
__device__ inline bf16  f2bf(float v){ return __float2bfloat16(v); }
__device__ inline float bfs2f(short s){ union{unsigned u; float f;} x; x.u = ((unsigned)(unsigned short)s)<<16; return x.f; }
__device__ inline short f2bfs(float v){ bf16 b = f2bf(v); return *reinterpret_cast<short*>(&b); }
__device__ inline float fast_sigmoid(float x){ return 1.0f/(1.0f+__expf(-x)); }
__device__ inline void stout(float* p, float v){ *p = v; }
__device__ inline void stout(bf16* p, float v){ *p = f2bf(v); }
// hardware 2^x / log2 (single-inst); libm exp2f/log1pf are the slow precise paths
__device__ inline float hw_exp2(float x){ float r; asm("v_exp_f32 %0, %1" : "=v"(r) : "v"(x)); return r; }
__device__ inline float hw_log2(float x){ float r; asm("v_log_f32 %0, %1" : "=v"(r) : "v"(x)); return r; }
__device__ inline float softplus_fast(float x){
  if (x > 15.0f) return x;
  return 0.69314718f * hw_log2(1.0f + hw_exp2(x * 1.44269504f));
}

__device__ inline void gload_lds16(const void* g, void* l){
  __builtin_amdgcn_global_load_lds((const gbl_t*)g, (lds_t*)l, 16, 0, 0);
}

// ---- transpose+cvt body: T[n][k] = W[k][col0+n] (n<nvalid else 0), 64x64 tile ----
__device__ inline void transpose_cvt_body(
    int bx, int by, const float* __restrict__ W, bf16* __restrict__ T,
    int ldw, int col0, int nvalid, int K, int tid, float (*tile)[65])
{
  int kb = bx << 6, nb = by << 6;
  int c = tid & 63, r4 = tid >> 6;
  #pragma unroll
  for (int i=0;i<16;i++){
    int r = r4 + i*4;
    int kk = kb + r, nn = nb + c;
    float v = 0.f;
    if (kk < K && nn < nvalid) v = W[(size_t)kk*ldw + col0 + nn];
    tile[r][c] = v;
  }
  __syncthreads();
  #pragma unroll
  for (int i=0;i<16;i++){
    int r = r4 + i*4;
    T[(size_t)(nb + r)*K + kb + c] = f2bf(tile[c][r]);
  }
}

// ---- merged prep: winT transpose | wxT | wdtT | posemb | cwT ----
__global__ __launch_bounds__(256) void k_prep_all(
    const float* __restrict__ W_in, bf16* __restrict__ winT,
    const float* __restrict__ W_x,  bf16* __restrict__ wxT,
    const float* __restrict__ W_dt, bf16* __restrict__ wdtT,
    float* __restrict__ pe,
    const float* __restrict__ cw, float* __restrict__ cwT)
{
  __shared__ float tile[64][65];
  int b = blockIdx.x, tid = threadIdx.x;
  if (b < 1024){
    transpose_cvt_body(b & 15, b >> 4, W_in, winT, 4096, 0, 4096, 1024, tid, tile);
  } else if (b < 1088){
    int t = b - 1024;
    transpose_cvt_body(t & 31, t >> 5, W_x, wxT, 96, 0, 96, 2048, tid, tile);
  } else if (b < 1120){
    int t = b - 1088;
    transpose_cvt_body(0, t, W_dt, wdtT, 2048, 0, 2048, 64, tid, tile);
  } else if (b < 3168){
    int idx = (b - 1120)*256 + tid;        // 512*1024 sincos table
    int n = idx >> 10, c = idx & 1023;
    int j2 = c & 511;
    float omega = exp2f(-13.2877123795495f * ((float)j2 * (1.0f/511.0f)));
    float ang = (float)n * omega;
    pe[idx] = (c < 512) ? sinf(ang) : cosf(ang);
  } else {
    int idx = (b - 3168)*256 + tid;        // 4*2048 conv-weight transpose
    int k = idx >> 11, d = idx & 2047;
    cwT[idx] = cw[d*4 + k];
  }
}

// ---- patch embedding: 16 tokens/block, Wp columns cached in registers ----
__global__ __launch_bounds__(256) void k_patch(
    const float* __restrict__ x, const float* __restrict__ g1, const float* __restrict__ b1,
    const float* __restrict__ Wp, const float* __restrict__ bp,
    const float* __restrict__ g2, const float* __restrict__ b2,
    const float* __restrict__ pe, bf16* __restrict__ h)
{
  __shared__ float pns[2][16];
  __shared__ float red[8];
  int tid = threadIdx.x;
  int w = tid >> 6, l = tid & 63;
  int tok0 = blockIdx.x << 4;         // 1024 blocks x 16 tokens (batch-aligned: 16|512)
  int bb = tok0 >> 9, n0 = tok0 & 511;
  float wreg[4][16];
  #pragma unroll
  for (int q=0;q<4;q++)
    #pragma unroll
    for (int i=0;i<16;i++)
      wreg[q][i] = Wp[i*1024 + tid + q*256];
  float bpv[4], g2v[4], b2v[4];
  #pragma unroll
  for (int q=0;q<4;q++){
    int j = tid + q*256;
    bpv[q] = bp[j]; g2v[q] = g2[j]; b2v[q] = b2[j];
  }
  float g1v = 0.f, b1v = 0.f;
  if (tid < 16){ g1v = g1[tid]; b1v = b1[tid]; }
  for (int tt=0; tt<16; ++tt){
    int buf = tt & 1;
    if (tid < 16){
      float v = x[(size_t)bb*CTX + (n0+tt)*16 + tid];
      float m = v;
      #pragma unroll
      for (int o=1;o<16;o<<=1) m += __shfl_xor(m, o, 64);
      m *= (1.0f/16.0f);
      float dv = v - m;
      float s = dv*dv;
      #pragma unroll
      for (int o=1;o<16;o<<=1) s += __shfl_xor(s, o, 64);
      float rs = rsqrtf(s*(1.0f/16.0f) + 1e-5f);
      pns[buf][tid] = dv*rs*g1v + b1v;
    }
    __syncthreads();
    float acc[4];
    #pragma unroll
    for (int q=0;q<4;q++) acc[q] = bpv[q];
    #pragma unroll
    for (int i=0;i<16;i++){
      float p = pns[buf][i];
      #pragma unroll
      for (int q=0;q<4;q++) acc[q] += p*wreg[q][i];
    }
    float s1 = acc[0]+acc[1]+acc[2]+acc[3];
    float s2 = acc[0]*acc[0]+acc[1]*acc[1]+acc[2]*acc[2]+acc[3]*acc[3];
    #pragma unroll
    for (int o=32;o;o>>=1){ s1 += __shfl_down(s1,o,64); s2 += __shfl_down(s2,o,64); }
    if (l==0){ red[w]=s1; red[4+w]=s2; }
    __syncthreads();
    float mu  = (red[0]+red[1]+red[2]+red[3])*(1.0f/1024.0f);
    float var = (red[4]+red[5]+red[6]+red[7])*(1.0f/1024.0f) - mu*mu;
    float rs2 = rsqrtf(var + 1e-5f);
    size_t tok = (size_t)(tok0 + tt);
    #pragma unroll
    for (int q=0;q<4;q++){
      int j = tid + q*256;
      float val = (acc[q]-mu)*rs2*g2v[q] + b2v[q] + pe[(n0+tt)*1024 + j];
      h[tok*1024 + j] = f2bf(val);
    }
  }
}

// ==== 256x256-tile 8-wave in_proj GEMM, counted-vmcnt double-buffer (T3+T4), ====
// ==== T2 swizzle, T5 setprio; B-fragments hoisted per kk.                     ====
__global__ __launch_bounds__(512, 2) void k_gemm256(
    const bf16* __restrict__ A, const bf16* __restrict__ BT,
    bf16* __restrict__ Cu, bf16* __restrict__ Cz, int M, int N, int K)
{
  __shared__ __align__(16) bf16 As[2][256*64];
  __shared__ __align__(16) bf16 Bs[2][256*64];
  const int tid = threadIdx.x;
  const int w = tid >> 6, l = tid & 63, lr = l & 15, lg = l >> 4;
  const int wm = w >> 2, wn = w & 3;
  int nblk = N >> 8;
  int nwg = gridDim.x;
  int wg  = (blockIdx.x & 7) * (nwg >> 3) + (blockIdx.x >> 3);
  const int GM = 4;
  int band = GM * nblk;
  int grp = wg / band, loc = wg % band;
  int bm = grp*GM + (loc % GM);
  int bn = loc / GM;
  int m0 = bm << 8, n0 = bn << 8;

  f32x4 acc[8][4] = {};

  int rowS[4], colS[4];
  #pragma unroll
  for (int j=0;j<4;j++){
    int bo = (j*8 + w)*1024 + l*16;
    int r = bo >> 7;
    int c = (bo & 127) ^ ((r & 7) << 4);
    rowS[j] = r; colS[j] = c >> 1;
  }
  const bf16* Ag = A  + (size_t)m0 * K;
  const bf16* Bg = BT + (size_t)n0 * K;

  #define STAGE(buf, kt) do {                                                   \
    _Pragma("unroll")                                                           \
    for (int j=0;j<4;j++)                                                       \
      gload_lds16(Ag + (size_t)rowS[j]*K + (kt) + colS[j], &As[buf][(j*8+w)*512]); \
    _Pragma("unroll")                                                           \
    for (int j=0;j<4;j++)                                                       \
      gload_lds16(Bg + (size_t)rowS[j]*K + (kt) + colS[j], &Bs[buf][(j*8+w)*512]); \
  } while(0)

  int cswz[2];
  cswz[0] = (lg*8) ^ ((lr&7)<<3);
  cswz[1] = (32 + lg*8) ^ ((lr&7)<<3);
  const int rbA = (wm*128 + lr) * 64;
  const int rbB = (wn*64  + lr) * 64;

  #define COMPUTE(buf) do {                                                     \
    _Pragma("unroll")                                                           \
    for (int kk=0;kk<2;kk++){                                                   \
      bf16x8 bq[4];                                                             \
      _Pragma("unroll")                                                         \
      for (int j=0;j<4;j++) bq[j] = *(const bf16x8*)&Bs[buf][rbB + j*1024 + cswz[kk]]; \
      _Pragma("unroll")                                                         \
      for (int rh=0;rh<2;rh++){                                                 \
        bf16x8 af[4];                                                           \
        _Pragma("unroll")                                                       \
        for (int i=0;i<4;i++) af[i] = *(const bf16x8*)&As[buf][rbA + (rh*4+i)*1024 + cswz[kk]]; \
        __builtin_amdgcn_s_setprio(1);                                          \
        _Pragma("unroll")                                                       \
        for (int i=0;i<4;i++)                                                   \
          _Pragma("unroll")                                                     \
          for (int j=0;j<4;j++)                                                 \
            acc[rh*4+i][j] = __builtin_amdgcn_mfma_f32_16x16x32_bf16(af[i], bq[j], acc[rh*4+i][j], 0,0,0); \
        __builtin_amdgcn_s_setprio(0);                                          \
      }                                                                         \
    }                                                                           \
  } while(0)

  STAGE(0, 0);
  STAGE(1, 64);
  const int NT2 = K >> 7;
  int kt = 0;
  for (int t=0; t<NT2; ++t){
    const bool last = (t == NT2-1);
    asm volatile("s_waitcnt vmcnt(8)" ::: "memory");
    __builtin_amdgcn_sched_barrier(0);
    asm volatile("s_barrier" ::: "memory");
    COMPUTE(0);
    asm volatile("s_barrier" ::: "memory");
    __builtin_amdgcn_sched_barrier(0);
    if (!last) STAGE(0, kt + 128);
    if (!last) { asm volatile("s_waitcnt vmcnt(8)" ::: "memory"); }
    else       { asm volatile("s_waitcnt vmcnt(0)" ::: "memory"); }
    __builtin_amdgcn_sched_barrier(0);
    asm volatile("s_barrier" ::: "memory");
    COMPUTE(1);
    if (!last){
      asm volatile("s_barrier" ::: "memory");
      __builtin_amdgcn_sched_barrier(0);
      STAGE(1, kt + 192);
    }
    kt += 128;
  }
  #undef STAGE
  #undef COMPUTE

  #pragma unroll
  for (int fr=0;fr<8;fr++)
    #pragma unroll
    for (int fc=0;fc<4;fc++)
      #pragma unroll
      for (int rr=0;rr<4;rr++){
        int row  = m0 + wm*128 + fr*16 + lg*4 + rr;
        int gcol = n0 + wn*64 + fc*16 + lr;
        float v = acc[fr][fc][rr];
        if (gcol < 2048) Cu[(size_t)row*2048 + gcol] = f2bf(v);
        else { v = v * fast_sigmoid(v); Cz[(size_t)row*2048 + gcol - 2048] = f2bf(v); }
      }
}

// ---- bf16 MFMA GEMM (legacy 128^2 BK=32): used for dt-GEMM (EPI=1) ----
template<int EPI, typename OT>
__global__ __launch_bounds__(256) void k_gemm_bt(
    const bf16* __restrict__ A, const bf16* __restrict__ BT, OT* __restrict__ C,
    bf16* __restrict__ C2, int M, int N, int K, const float* __restrict__ bias)
{
  __shared__ __align__(16) bf16 As[128*32];
  __shared__ __align__(16) bf16 Bs[128*32];
  int tid = threadIdx.x;
  int mblk = M >> 7, nblk = N >> 7;
  int nwg = gridDim.x;
  int wg  = (blockIdx.x & 7) * (nwg >> 3) + (blockIdx.x >> 3);
  const int GM = 8;
  int band = GM * nblk;
  int grp = wg / band, loc = wg % band;
  int bm = grp*GM + (loc % GM);
  int bn = loc / GM;
  int m0 = bm << 7, n0 = bn << 7;
  int w = tid >> 6, l = tid & 63, lr = l & 15, lg = l >> 4;
  int wm = w >> 1, wn = w & 1;
  f32x4 acc[4][4] = {};
  int r0 = tid >> 2, c0 = (tid & 3) << 3;
  const bf16* Asrc = A  + (size_t)(m0 + r0) * K + c0;
  const bf16* Bsrc = BT + (size_t)(n0 + r0) * K + c0;
  bf16* AsW = As + w*512;
  bf16* BsW = Bs + w*512;
  for (int kt = 0; kt < K; kt += 32){
    __syncthreads();
    gload_lds16(Asrc + kt,                   AsW);
    gload_lds16(Asrc + (size_t)64*K + kt,    AsW + 2048);
    gload_lds16(Bsrc + kt,                   BsW);
    gload_lds16(Bsrc + (size_t)64*K + kt,    BsW + 2048);
    __syncthreads();
    bf16x8 af[4], bfr[4];
    #pragma unroll
    for (int i=0;i<4;i++) af[i]  = *(const bf16x8*)(As + (wm*64 + i*16 + lr)*32 + lg*8);
    #pragma unroll
    for (int j=0;j<4;j++) bfr[j] = *(const bf16x8*)(Bs + (wn*64 + j*16 + lr)*32 + lg*8);
    #pragma unroll
    for (int i=0;i<4;i++)
      #pragma unroll
      for (int j=0;j<4;j++)
        acc[i][j] = __builtin_amdgcn_mfma_f32_16x16x32_bf16(af[i], bfr[j], acc[i][j], 0,0,0);
  }
  #pragma unroll
  for (int i=0;i<4;i++)
    #pragma unroll
    for (int j=0;j<4;j++)
      #pragma unroll
      for (int r=0;r<4;r++){
        int row = m0 + wm*64 + i*16 + lg*4 + r;
        int col = wn*64 + j*16 + lr;
        int gcol = n0 + col;
        float v = acc[i][j][r];
        if (EPI == 0) stout(&C[(size_t)row*N + gcol], v);
        if (EPI == 1){ v = softplus_fast(v + bias[gcol]); stout(&C[(size_t)row*N + gcol], v); }
      }
}

// ---- x_proj split-K x4 GEMM (BK=32): chunk c covers K in [c*512, c*512+512) ----
__global__ __launch_bounds__(256) void k_gemm_xk(
    const bf16* __restrict__ A, const bf16* __restrict__ BT,
    float* __restrict__ C0, float* __restrict__ C1,
    float* __restrict__ C2, float* __restrict__ C3)
{
  __shared__ __align__(16) bf16 As[128*32];
  __shared__ __align__(16) bf16 Bs[128*32];
  int tid = threadIdx.x;
  int nwg = gridDim.x;
  int wg  = (blockIdx.x & 7) * (nwg >> 3) + (blockIdx.x >> 3);
  int chunk = wg >> 7;
  int bm = wg & 127;
  int m0 = bm << 7;
  int kbase = chunk << 9;
  int w = tid >> 6, l = tid & 63, lr = l & 15, lg = l >> 4;
  int wm = w >> 1, wn = w & 1;
  f32x4 acc[4][4] = {};
  int r0 = tid >> 2, c0 = (tid & 3) << 3;
  const bf16* Asrc = A  + (size_t)(m0 + r0) * 2048 + kbase + c0;
  const bf16* Bsrc = BT + (size_t)r0 * 2048 + kbase + c0;
  bf16* AsW = As + w*512;
  bf16* BsW = Bs + w*512;
  float* Cp = (chunk==0) ? C0 : (chunk==1) ? C1 : (chunk==2) ? C2 : C3;
  for (int kt = 0; kt < 512; kt += 32){
    __syncthreads();
    gload_lds16(Asrc + kt,                      AsW);
    gload_lds16(Asrc + (size_t)64*2048 + kt,    AsW + 2048);
    gload_lds16(Bsrc + kt,                      BsW);
    gload_lds16(Bsrc + (size_t)64*2048 + kt,    BsW + 2048);
    __syncthreads();
    bf16x8 af[4], bfr[4];
    #pragma unroll
    for (int i=0;i<4;i++) af[i]  = *(const bf16x8*)(As + (wm*64 + i*16 + lr)*32 + lg*8);
    #pragma unroll
    for (int j=0;j<4;j++) bfr[j] = *(const bf16x8*)(Bs + (wn*64 + j*16 + lr)*32 + lg*8);
    #pragma unroll
    for (int i=0;i<4;i++)
      #pragma unroll
      for (int j=0;j<4;j++)
        acc[i][j] = __builtin_amdgcn_mfma_f32_16x16x32_bf16(af[i], bfr[j], acc[i][j], 0,0,0);
  }
  #pragma unroll
  for (int i=0;i<4;i++)
    #pragma unroll
    for (int j=0;j<4;j++)
      #pragma unroll
      for (int r=0;r<4;r++){
        int row = m0 + wm*64 + i*16 + lg*4 + r;
        int gcol = wn*64 + j*16 + lr;
        Cp[(size_t)row*128 + gcol] = acc[i][j][r];
      }
}

// ---- x_proj fixup: xd = p0+p1+p2+p3 (in place into xd); dt = bf16(xd[:, :64]) ----
__global__ __launch_bounds__(256) void k_xproj_fix(
    float* __restrict__ xd, const float* __restrict__ p1,
    const float* __restrict__ p2, const float* __restrict__ p3,
    bf16* __restrict__ dt)
{
  int idx = blockIdx.x*256 + threadIdx.x;   // 16384*128
  int row = idx >> 7, col = idx & 127;
  float v = xd[idx] + p1[idx] + p2[idx] + p3[idx];
  xd[idx] = v;
  if (col < 64) dt[(row << 6) + col] = f2bf(v);
}

// ---- causal depthwise conv (DC=4) + SiLU, sliding-window vectorized ----
__global__ __launch_bounds__(256) void k_conv(
    const bf16* __restrict__ u, const float* __restrict__ cwT, const float* __restrict__ cb,
    bf16* __restrict__ uc)
{
  int tid = threadIdx.x;
  int d = tid << 3;
  int tok0 = blockIdx.x << 4;       // 1024 blocks x 16 tokens
  int n0 = tok0 & 511;              // position within batch
  float wk[4][8];
  #pragma unroll
  for (int k=0;k<4;k++){
    *(float4*)&wk[k][0] = *(const float4*)(cwT + k*2048 + d);
    *(float4*)&wk[k][4] = *(const float4*)(cwT + k*2048 + d + 4);
  }
  float cbv[8];
  *(float4*)&cbv[0] = *(const float4*)(cb + d);
  *(float4*)&cbv[4] = *(const float4*)(cb + d + 4);
  bf16x8 w0, w1, w2;
  if (n0 == 0){
    w0 = (bf16x8){0,0,0,0,0,0,0,0}; w1 = w0; w2 = w0;
  } else {
    w0 = *(const bf16x8*)(u + (size_t)(tok0-3)*2048 + d);
    w1 = *(const bf16x8*)(u + (size_t)(tok0-2)*2048 + d);
    w2 = *(const bf16x8*)(u + (size_t)(tok0-1)*2048 + d);
  }
  #pragma unroll 4
  for (int t=0; t<16; ++t){
    size_t tok = (size_t)(tok0 + t);
    bf16x8 cur = *(const bf16x8*)(u + tok*2048 + d);
    bf16x8 res;
    #pragma unroll
    for (int j=0;j<8;j++){
      float a = cbv[j]
              + wk[0][j]*bfs2f(w0[j]) + wk[1][j]*bfs2f(w1[j])
              + wk[2][j]*bfs2f(w2[j]) + wk[3][j]*bfs2f(cur[j]);
      res[j] = f2bfs(a * fast_sigmoid(a));
    }
    *(bf16x8*)(uc + tok*2048 + d) = res;
    w0 = w1; w1 = w2; w2 = cur;
  }
}

// ---- selective scan: wave-per-state-quad mapping, scalar B/C loads ----
// Block = 4 waves; wave w = state quad q (wave-uniform), 64 lanes = 64 d.
// B/C xd loads are wave-uniform (readfirstlane) -> scalar pipe; per-wave VMEM
// drops 5->3 per t. Cross-q reduce via LDS at the end.
__global__ __launch_bounds__(256) void k_scan(
    const bf16* __restrict__ delta, const bf16* __restrict__ uc, const bf16* __restrict__ g,
    const float* __restrict__ xd, const float* __restrict__ A_log,
    const float* __restrict__ Dp, float* __restrict__ ysum)
{
  __shared__ float red[4][64];
  int tid = threadIdx.x;
  int q = tid >> 6;          // wave id = state quad (uniform within wave)
  int l = tid & 63;          // d within the block's 64-d slab
  int b = blockIdx.x >> 5;
  int d = ((blockIdx.x & 31) << 6) + l;
  const float L2E = 1.44269504f;
  float4 t4 = *(const float4*)(A_log + (size_t)d*16 + q*4);
  float An0 = -__expf(t4.x)*L2E, An1 = -__expf(t4.y)*L2E,
        An2 = -__expf(t4.z)*L2E, An3 = -__expf(t4.w)*L2E;
  float Dd = (q == 0) ? Dp[d] : 0.0f;
  float h0=0.f,h1=0.f,h2=0.f,h3=0.f;
  float acc = 0.0f;
  unsigned o1 = (unsigned)b*1048576u + (unsigned)d;       // elem offset delta/uc/g
  // float4 index into xd: wave-uniform (b, q fixed; t advances) -> scalar loads
  unsigned o2 = (unsigned)__builtin_amdgcn_readfirstlane((unsigned)(b*16384 + 16 + q));
  const float4* __restrict__ x4 = (const float4*)xd;
  #pragma unroll 4
  for (int t=0; t<512; ++t){
    float dt = bf2f(delta[o1]);
    float ut = bf2f(uc[o1]);
    float gt = bf2f(g[o1]);
    float4 Bq = x4[o2];
    float4 Cq = x4[o2 + 4u];
    o1 += 2048u; o2 += 32u;
    float du = dt*ut;
    float y;
    float e0 = hw_exp2(dt*An0); h0 = h0*e0 + du*Bq.x; y  = h0*Cq.x;
    float e1 = hw_exp2(dt*An1); h1 = h1*e1 + du*Bq.y; y += h1*Cq.y;
    float e2 = hw_exp2(dt*An2); h2 = h2*e2 + du*Bq.z; y += h2*Cq.z;
    float e3 = hw_exp2(dt*An3); h3 = h3*e3 + du*Bq.w; y += h3*Cq.w;
    acc += (y + ut*Dd) * gt;
  }
  red[q][l] = acc;
  __syncthreads();
  if (q == 0)
    ysum[(size_t)b*2048 + d] = red[0][l] + red[1][l] + red[2][l] + red[3][l];
}

// ---- split-K pooled GEMM part 1 ----
__global__ __launch_bounds__(256) void k_poolgemm_part(
    const float* __restrict__ ysum, const float* __restrict__ Wo, float* __restrict__ partial)
{
  __shared__ float ys[32][64];
  int tid = threadIdx.x;
  int jb = blockIdx.x & 15;
  int kc = blockIdx.x >> 4;
  int j  = jb*64 + (tid & 63);
  int b0 = tid >> 6;
  #pragma unroll
  for (int i=0;i<8;i++){
    int e = tid + i*256;
    int bb = e >> 6, kk = e & 63;
    ys[bb][kk] = ysum[(size_t)bb*2048 + kc*64 + kk];
  }
  __syncthreads();
  float acc[8];
  #pragma unroll
  for (int p=0;p<8;p++) acc[p] = 0.f;
  #pragma unroll 4
  for (int kk=0;kk<64;kk++){
    float wv = Wo[(size_t)(kc*64 + kk)*1024 + j];
    #pragma unroll
    for (int p=0;p<8;p++) acc[p] += ys[b0*8 + p][kk] * wv;
  }
  #pragma unroll
  for (int p=0;p<8;p++)
    partial[((size_t)kc*32 + b0*8 + p)*1024 + j] = acc[p];
}

// ---- split-K pooled GEMM part 2 ----
__global__ __launch_bounds__(256) void k_pool_reduce(
    const float* __restrict__ partial, float* __restrict__ pooled)
{
  int idx = blockIdx.x*256 + threadIdx.x;    // 32768
  float s = 0.f;
  #pragma unroll 8
  for (int kc=0;kc<32;kc++) s += partial[(size_t)kc*32768 + idx];
  pooled[idx] = s * (1.0f/512.0f);
}

// ---- head: LN(1024) -> dot Wh + bh ----
__global__ __launch_bounds__(256) void k_head(
    const float* __restrict__ pooled, const float* __restrict__ g, const float* __restrict__ bb,
    const float* __restrict__ Wh, const float* __restrict__ bh, float* __restrict__ out)
{
  __shared__ float red[8];
  int b = blockIdx.x, tid = threadIdx.x;
  float v[4];
  #pragma unroll
  for (int q=0;q<4;q++) v[q] = pooled[(size_t)b*1024 + tid + q*256];
  float s1 = v[0]+v[1]+v[2]+v[3];
  float s2 = v[0]*v[0]+v[1]*v[1]+v[2]*v[2]+v[3]*v[3];
  #pragma unroll
  for (int o=32;o;o>>=1){ s1 += __shfl_down(s1,o,64); s2 += __shfl_down(s2,o,64); }
  int w = tid>>6, l = tid&63;
  if (l==0){ red[w]=s1; red[4+w]=s2; }
  __syncthreads();
  float mu  = (red[0]+red[1]+red[2]+red[3])*(1.0f/1024.0f);
  float var = (red[4]+red[5]+red[6]+red[7])*(1.0f/1024.0f) - mu*mu;
  float rs = rsqrtf(var + 1e-5f);
  float p = 0.f;
  #pragma unroll
  for (int q=0;q<4;q++){
    int jv = tid + q*256;
    p += ((v[q]-mu)*rs*g[jv] + bb[jv]) * Wh[jv];
  }
  #pragma unroll
  for (int o=32;o;o>>=1) p += __shfl_down(p,o,64);
  __syncthreads();
  if (l==0) red[w] = p;
  __syncthreads();
  if (tid==0) out[b] = red[0]+red[1]+red[2]+red[3] + bh[0];
}

extern "C" void kernel_launch(void* const* d_in, const int* in_sizes, int n_in,
                              void* d_out, int out_size, void* d_ws, size_t ws_size,
                              hipStream_t stream)
{
  const float* x     = (const float*)d_in[0];
  const float* ln1_g = (const float*)d_in[1];
  const float* ln1_b = (const float*)d_in[2];
  const float* Wp    = (const float*)d_in[3];
  const float* bp    = (const float*)d_in[4];
  const float* ln2_g = (const float*)d_in[5];
  const float* ln2_b = (const float*)d_in[6];
  const float* W_in  = (const float*)d_in[7];
  const float* conv_w= (const float*)d_in[8];
  const float* conv_b= (const float*)d_in[9];
  const float* W_x   = (const float*)d_in[10];
  const float* W_dt  = (const float*)d_in[11];
  const float* b_dt  = (const float*)d_in[12];
  const float* A_log = (const float*)d_in[13];
  const float* Dv    = (const float*)d_in[14];
  const float* W_out = (const float*)d_in[15];
  const float* ln3_g = (const float*)d_in[16];
  const float* ln3_b = (const float*)d_in[17];
  const float* Wh    = (const float*)d_in[18];
  const float* bh    = (const float*)d_in[19];

  // ---- workspace layout with liveness-based aliasing; peak ~234.8 MiB ----
  char* ws = (char*)d_ws;
  size_t o = 0;
  bf16*  u_delta = (bf16*)(ws + o); o += (size_t)NTOK*DI_*2;   // 64 MiB: u, then xpart2/3, then delta
  bf16*  zbuf    = (bf16*)(ws + o); o += (size_t)NTOK*DI_*2;   // 64 MiB: g = silu(z)
  bf16*  ucbuf   = (bf16*)(ws + o); o += (size_t)NTOK*DI_*2;   // 64 MiB: uc (persistent)
  char*  poolA   = (ws + o);        o += (size_t)NTOK*DM_*2;   // 32 MiB: h, later xd/dt/...
  bf16*  winT    = (bf16*)(ws + o); o += (size_t)2*DI_*DM_*2;  //  8 MiB: in_proj^T; later xpart1
  float* pe      = (float*)(ws + o); o += (size_t)NP_*DM_*4;   //  2 MiB
  bf16*  wxT     = (bf16*)(ws + o); o += (size_t)128*2048*2;   //  0.5 MiB (dedicated; no alias)
  bf16*  wdtT    = (bf16*)(ws + o); o += (size_t)2048*64*2;    //  0.25 MiB
  float* cwT     = (float*)(ws + o); o += (size_t)4*2048*4;    //  32 KiB
  bf16*  hbuf    = (bf16*)poolA;                 // phase-1
  float* xdbuf   = (float*)(poolA + 0);          // 8.0 MiB  [16384,128] f32
  bf16*  dtbuf   = (bf16*) (poolA + 8388608);    // 2.0 MiB  [16384,64]
  float* ysumbuf = (float*)(poolA + 11272192);   // 0.25 MiB [32,2048]
  float* pooledb = (float*)(poolA + 11534336);   // 0.13 MiB [32,1024]
  float* partial = (float*)(poolA + 12582912);   // 4.0 MiB  [32,32,1024]
  float* xpart1  = (float*)winT;                 // 8.0 MiB  (winT dead after gemm256)
  float* xpart2  = (float*)u_delta;              // 8.0 MiB  (u dead after conv)
  float* xpart3  = (float*)((char*)u_delta + 8388608); // 8.0 MiB

  // all weight preps + posemb in one kernel (saves 4 launches)
  k_prep_all      <<<3200, 256, 0, stream>>>(W_in, winT, W_x, wxT, W_dt, wdtT, pe, conv_w, cwT);
  k_patch         <<<1024, 256, 0, stream>>>(x, ln1_g, ln1_b, Wp, bp, ln2_g, ln2_b, pe, hbuf);
  // merged in_proj via 256^2 8-wave counted-vmcnt kernel
  k_gemm256       <<<1024, 512, 0, stream>>>(hbuf, winT, u_delta, zbuf, NTOK, 4096, 1024);
  // conv(u) -> uc   (hbuf + u dead from here)
  k_conv          <<<1024, 256, 0, stream>>>(u_delta, cwT, conv_b, ucbuf);
  // x_proj: split-K x4 (partials in dead winT + u_delta), then fixup emits xd + dt
  k_gemm_xk       <<<512,  256, 0, stream>>>(ucbuf, wxT, xdbuf, xpart1, xpart2, xpart3);
  k_xproj_fix     <<<8192, 256, 0, stream>>>(xdbuf, xpart1, xpart2, xpart3, dtbuf);
  // delta = softplus(dt @ W_dt + b_dt)  (overwrites u_delta; xparts dead)
  k_gemm_bt<1,bf16><<<2048,256, 0, stream>>>(dtbuf, wdtT, u_delta, nullptr, NTOK, 2048, 64, b_dt);
  // fused scan + D-skip + gate + token-sum (wave-per-q, scalar B/C loads)
  k_scan          <<<1024, 256, 0, stream>>>(u_delta, ucbuf, zbuf, xdbuf, A_log, Dv, ysumbuf);
  // pooled = (ysum/512) @ W_out : split-K over 512 blocks, then reduce
  k_poolgemm_part <<<512,  256, 0, stream>>>(ysumbuf, W_out, partial);
  k_pool_reduce   <<<128,  256, 0, stream>>>(partial, pooledb);
  k_head          <<<32,   256, 0, stream>>>(pooledb, ln3_g, ln3_b, Wh, bh, (float*)d_out);
  (void)in_sizes; (void)n_in; (void)out_size; (void)ws_size;
}

// Round 18
// 436.488 us; speedup vs baseline: 1.1669x; 1.0036x over previous
//
#include <hip/hip_runtime.h>
#include <hip/hip_bf16.h>

// ---- problem constants ----
#define BSZ  32
#define CTX  8192
#define NP_  512
#define PSZ  16
#define DM_  1024
#define DS_  16
#define DI_  2048
#define DTR_ 64
#define NTOK (BSZ*NP_)   // 16384

typedef __hip_bfloat16 bf16;
typedef short bf16x8 __attribute__((ext_vector_type(8)));
typedef float f32x4  __attribute__((ext_vector_type(4)));

typedef __attribute__((address_space(3))) void lds_t;
typedef __attribute__((address_space(1))) void gbl_t;

__device__ inline float bf2f(bf16 v){ return __bfloat162float(v); }
__device__ inline bf16  f2bf(float v){ return __float2bfloat16(v); }
__device__ inline float bfs2f(short s){ union{unsigned u; float f;} x; x.u = ((unsigned)(unsigned short)s)<<16; return x.f; }
__device__ inline short f2bfs(float v){ bf16 b = f2bf(v); return *reinterpret_cast<short*>(&b); }
__device__ inline float fast_sigmoid(float x){ return 1.0f/(1.0f+__expf(-x)); }
__device__ inline void stout(float* p, float v){ *p = v; }
__device__ inline void stout(bf16* p, float v){ *p = f2bf(v); }
// hardware 2^x / log2 (single-inst); libm exp2f/log1pf are the slow precise paths
__device__ inline float hw_exp2(float x){ float r; asm("v_exp_f32 %0, %1" : "=v"(r) : "v"(x)); return r; }
__device__ inline float hw_log2(float x){ float r; asm("v_log_f32 %0, %1" : "=v"(r) : "v"(x)); return r; }
__device__ inline float softplus_fast(float x){
  if (x > 15.0f) return x;
  return 0.69314718f * hw_log2(1.0f + hw_exp2(x * 1.44269504f));
}

__device__ inline void gload_lds16(const void* g, void* l){
  __builtin_amdgcn_global_load_lds((const gbl_t*)g, (lds_t*)l, 16, 0, 0);
}

// ---- transpose+cvt body: T[n][k] = W[k][col0+n] (n<nvalid else 0), 64x64 tile ----
__device__ inline void transpose_cvt_body(
    int bx, int by, const float* __restrict__ W, bf16* __restrict__ T,
    int ldw, int col0, int nvalid, int K, int tid, float (*tile)[65])
{
  int kb = bx << 6, nb = by << 6;
  int c = tid & 63, r4 = tid >> 6;
  #pragma unroll
  for (int i=0;i<16;i++){
    int r = r4 + i*4;
    int kk = kb + r, nn = nb + c;
    float v = 0.f;
    if (kk < K && nn < nvalid) v = W[(size_t)kk*ldw + col0 + nn];
    tile[r][c] = v;
  }
  __syncthreads();
  #pragma unroll
  for (int i=0;i<16;i++){
    int r = r4 + i*4;
    T[(size_t)(nb + r)*K + kb + c] = f2bf(tile[c][r]);
  }
}

// ---- merged prep: winT transpose | wxT | wdtT | posemb | cwT ----
__global__ __launch_bounds__(256) void k_prep_all(
    const float* __restrict__ W_in, bf16* __restrict__ winT,
    const float* __restrict__ W_x,  bf16* __restrict__ wxT,
    const float* __restrict__ W_dt, bf16* __restrict__ wdtT,
    float* __restrict__ pe,
    const float* __restrict__ cw, float* __restrict__ cwT)
{
  __shared__ float tile[64][65];
  int b = blockIdx.x, tid = threadIdx.x;
  if (b < 1024){
    transpose_cvt_body(b & 15, b >> 4, W_in, winT, 4096, 0, 4096, 1024, tid, tile);
  } else if (b < 1088){
    int t = b - 1024;
    transpose_cvt_body(t & 31, t >> 5, W_x, wxT, 96, 0, 96, 2048, tid, tile);
  } else if (b < 1120){
    int t = b - 1088;
    transpose_cvt_body(0, t, W_dt, wdtT, 2048, 0, 2048, 64, tid, tile);
  } else if (b < 3168){
    int idx = (b - 1120)*256 + tid;        // 512*1024 sincos table
    int n = idx >> 10, c = idx & 1023;
    int j2 = c & 511;
    float omega = exp2f(-13.2877123795495f * ((float)j2 * (1.0f/511.0f)));
    float ang = (float)n * omega;
    pe[idx] = (c < 512) ? sinf(ang) : cosf(ang);
  } else {
    int idx = (b - 3168)*256 + tid;        // 4*2048 conv-weight transpose
    int k = idx >> 11, d = idx & 2047;
    cwT[idx] = cw[d*4 + k];
  }
}

// ---- patch embedding: 16 tokens/block, Wp columns cached in registers ----
__global__ __launch_bounds__(256) void k_patch(
    const float* __restrict__ x, const float* __restrict__ g1, const float* __restrict__ b1,
    const float* __restrict__ Wp, const float* __restrict__ bp,
    const float* __restrict__ g2, const float* __restrict__ b2,
    const float* __restrict__ pe, bf16* __restrict__ h)
{
  __shared__ float pns[2][16];
  __shared__ float red[8];
  int tid = threadIdx.x;
  int w = tid >> 6, l = tid & 63;
  int tok0 = blockIdx.x << 4;         // 1024 blocks x 16 tokens (batch-aligned: 16|512)
  int bb = tok0 >> 9, n0 = tok0 & 511;
  float wreg[4][16];
  #pragma unroll
  for (int q=0;q<4;q++)
    #pragma unroll
    for (int i=0;i<16;i++)
      wreg[q][i] = Wp[i*1024 + tid + q*256];
  float bpv[4], g2v[4], b2v[4];
  #pragma unroll
  for (int q=0;q<4;q++){
    int j = tid + q*256;
    bpv[q] = bp[j]; g2v[q] = g2[j]; b2v[q] = b2[j];
  }
  float g1v = 0.f, b1v = 0.f;
  if (tid < 16){ g1v = g1[tid]; b1v = b1[tid]; }
  for (int tt=0; tt<16; ++tt){
    int buf = tt & 1;
    if (tid < 16){
      float v = x[(size_t)bb*CTX + (n0+tt)*16 + tid];
      float m = v;
      #pragma unroll
      for (int o=1;o<16;o<<=1) m += __shfl_xor(m, o, 64);
      m *= (1.0f/16.0f);
      float dv = v - m;
      float s = dv*dv;
      #pragma unroll
      for (int o=1;o<16;o<<=1) s += __shfl_xor(s, o, 64);
      float rs = rsqrtf(s*(1.0f/16.0f) + 1e-5f);
      pns[buf][tid] = dv*rs*g1v + b1v;
    }
    __syncthreads();
    float acc[4];
    #pragma unroll
    for (int q=0;q<4;q++) acc[q] = bpv[q];
    #pragma unroll
    for (int i=0;i<16;i++){
      float p = pns[buf][i];
      #pragma unroll
      for (int q=0;q<4;q++) acc[q] += p*wreg[q][i];
    }
    float s1 = acc[0]+acc[1]+acc[2]+acc[3];
    float s2 = acc[0]*acc[0]+acc[1]*acc[1]+acc[2]*acc[2]+acc[3]*acc[3];
    #pragma unroll
    for (int o=32;o;o>>=1){ s1 += __shfl_down(s1,o,64); s2 += __shfl_down(s2,o,64); }
    if (l==0){ red[w]=s1; red[4+w]=s2; }
    __syncthreads();
    float mu  = (red[0]+red[1]+red[2]+red[3])*(1.0f/1024.0f);
    float var = (red[4]+red[5]+red[6]+red[7])*(1.0f/1024.0f) - mu*mu;
    float rs2 = rsqrtf(var + 1e-5f);
    size_t tok = (size_t)(tok0 + tt);
    #pragma unroll
    for (int q=0;q<4;q++){
      int j = tid + q*256;
      float val = (acc[q]-mu)*rs2*g2v[q] + b2v[q] + pe[(n0+tt)*1024 + j];
      h[tok*1024 + j] = f2bf(val);
    }
  }
}

// ==== 256x256-tile 8-wave in_proj GEMM, counted-vmcnt double-buffer (T3+T4), ====
// ==== T2 swizzle, T5 setprio; B-fragments hoisted per kk. BK=64, 128KiB LDS. ====
// NOTE r17: BK=32 + launch_bounds(512,4) NaN'd — forced spills emit scratch VMEM
// that corrupts counted-vmcnt; and the 128-float acc pins >=2 waves/SIMD anyway.
__global__ __launch_bounds__(512, 2) void k_gemm256(
    const bf16* __restrict__ A, const bf16* __restrict__ BT,
    bf16* __restrict__ Cu, bf16* __restrict__ Cz, int M, int N, int K)
{
  __shared__ __align__(16) bf16 As[2][256*64];
  __shared__ __align__(16) bf16 Bs[2][256*64];
  const int tid = threadIdx.x;
  const int w = tid >> 6, l = tid & 63, lr = l & 15, lg = l >> 4;
  const int wm = w >> 2, wn = w & 3;
  int nblk = N >> 8;
  int nwg = gridDim.x;
  int wg  = (blockIdx.x & 7) * (nwg >> 3) + (blockIdx.x >> 3);
  const int GM = 4;
  int band = GM * nblk;
  int grp = wg / band, loc = wg % band;
  int bm = grp*GM + (loc % GM);
  int bn = loc / GM;
  int m0 = bm << 8, n0 = bn << 8;

  f32x4 acc[8][4] = {};

  int rowS[4], colS[4];
  #pragma unroll
  for (int j=0;j<4;j++){
    int bo = (j*8 + w)*1024 + l*16;
    int r = bo >> 7;
    int c = (bo & 127) ^ ((r & 7) << 4);
    rowS[j] = r; colS[j] = c >> 1;
  }
  const bf16* Ag = A  + (size_t)m0 * K;
  const bf16* Bg = BT + (size_t)n0 * K;

  #define STAGE(buf, kt) do {                                                   \
    _Pragma("unroll")                                                           \
    for (int j=0;j<4;j++)                                                       \
      gload_lds16(Ag + (size_t)rowS[j]*K + (kt) + colS[j], &As[buf][(j*8+w)*512]); \
    _Pragma("unroll")                                                           \
    for (int j=0;j<4;j++)                                                       \
      gload_lds16(Bg + (size_t)rowS[j]*K + (kt) + colS[j], &Bs[buf][(j*8+w)*512]); \
  } while(0)

  int cswz[2];
  cswz[0] = (lg*8) ^ ((lr&7)<<3);
  cswz[1] = (32 + lg*8) ^ ((lr&7)<<3);
  const int rbA = (wm*128 + lr) * 64;
  const int rbB = (wn*64  + lr) * 64;

  #define COMPUTE(buf) do {                                                     \
    _Pragma("unroll")                                                           \
    for (int kk=0;kk<2;kk++){                                                   \
      bf16x8 bq[4];                                                             \
      _Pragma("unroll")                                                         \
      for (int j=0;j<4;j++) bq[j] = *(const bf16x8*)&Bs[buf][rbB + j*1024 + cswz[kk]]; \
      _Pragma("unroll")                                                         \
      for (int rh=0;rh<2;rh++){                                                 \
        bf16x8 af[4];                                                           \
        _Pragma("unroll")                                                       \
        for (int i=0;i<4;i++) af[i] = *(const bf16x8*)&As[buf][rbA + (rh*4+i)*1024 + cswz[kk]]; \
        __builtin_amdgcn_s_setprio(1);                                          \
        _Pragma("unroll")                                                       \
        for (int i=0;i<4;i++)                                                   \
          _Pragma("unroll")                                                     \
          for (int j=0;j<4;j++)                                                 \
            acc[rh*4+i][j] = __builtin_amdgcn_mfma_f32_16x16x32_bf16(af[i], bq[j], acc[rh*4+i][j], 0,0,0); \
        __builtin_amdgcn_s_setprio(0);                                          \
      }                                                                         \
    }                                                                           \
  } while(0)

  STAGE(0, 0);
  STAGE(1, 64);
  const int NT2 = K >> 7;
  int kt = 0;
  for (int t=0; t<NT2; ++t){
    const bool last = (t == NT2-1);
    asm volatile("s_waitcnt vmcnt(8)" ::: "memory");
    __builtin_amdgcn_sched_barrier(0);
    asm volatile("s_barrier" ::: "memory");
    COMPUTE(0);
    asm volatile("s_barrier" ::: "memory");
    __builtin_amdgcn_sched_barrier(0);
    if (!last) STAGE(0, kt + 128);
    if (!last) { asm volatile("s_waitcnt vmcnt(8)" ::: "memory"); }
    else       { asm volatile("s_waitcnt vmcnt(0)" ::: "memory"); }
    __builtin_amdgcn_sched_barrier(0);
    asm volatile("s_barrier" ::: "memory");
    COMPUTE(1);
    if (!last){
      asm volatile("s_barrier" ::: "memory");
      __builtin_amdgcn_sched_barrier(0);
      STAGE(1, kt + 192);
    }
    kt += 128;
  }
  #undef STAGE
  #undef COMPUTE

  #pragma unroll
  for (int fr=0;fr<8;fr++)
    #pragma unroll
    for (int fc=0;fc<4;fc++)
      #pragma unroll
      for (int rr=0;rr<4;rr++){
        int row  = m0 + wm*128 + fr*16 + lg*4 + rr;
        int gcol = n0 + wn*64 + fc*16 + lr;
        float v = acc[fr][fc][rr];
        if (gcol < 2048) Cu[(size_t)row*2048 + gcol] = f2bf(v);
        else { v = v * fast_sigmoid(v); Cz[(size_t)row*2048 + gcol - 2048] = f2bf(v); }
      }
}

// ---- bf16 MFMA GEMM (legacy 128^2 BK=32): used for dt-GEMM (EPI=1) ----
template<int EPI, typename OT>
__global__ __launch_bounds__(256) void k_gemm_bt(
    const bf16* __restrict__ A, const bf16* __restrict__ BT, OT* __restrict__ C,
    bf16* __restrict__ C2, int M, int N, int K, const float* __restrict__ bias)
{
  __shared__ __align__(16) bf16 As[128*32];
  __shared__ __align__(16) bf16 Bs[128*32];
  int tid = threadIdx.x;
  int mblk = M >> 7, nblk = N >> 7;
  int nwg = gridDim.x;
  int wg  = (blockIdx.x & 7) * (nwg >> 3) + (blockIdx.x >> 3);
  const int GM = 8;
  int band = GM * nblk;
  int grp = wg / band, loc = wg % band;
  int bm = grp*GM + (loc % GM);
  int bn = loc / GM;
  int m0 = bm << 7, n0 = bn << 7;
  int w = tid >> 6, l = tid & 63, lr = l & 15, lg = l >> 4;
  int wm = w >> 1, wn = w & 1;
  f32x4 acc[4][4] = {};
  int r0 = tid >> 2, c0 = (tid & 3) << 3;
  const bf16* Asrc = A  + (size_t)(m0 + r0) * K + c0;
  const bf16* Bsrc = BT + (size_t)(n0 + r0) * K + c0;
  bf16* AsW = As + w*512;
  bf16* BsW = Bs + w*512;
  for (int kt = 0; kt < K; kt += 32){
    __syncthreads();
    gload_lds16(Asrc + kt,                   AsW);
    gload_lds16(Asrc + (size_t)64*K + kt,    AsW + 2048);
    gload_lds16(Bsrc + kt,                   BsW);
    gload_lds16(Bsrc + (size_t)64*K + kt,    BsW + 2048);
    __syncthreads();
    bf16x8 af[4], bfr[4];
    #pragma unroll
    for (int i=0;i<4;i++) af[i]  = *(const bf16x8*)(As + (wm*64 + i*16 + lr)*32 + lg*8);
    #pragma unroll
    for (int j=0;j<4;j++) bfr[j] = *(const bf16x8*)(Bs + (wn*64 + j*16 + lr)*32 + lg*8);
    #pragma unroll
    for (int i=0;i<4;i++)
      #pragma unroll
      for (int j=0;j<4;j++)
        acc[i][j] = __builtin_amdgcn_mfma_f32_16x16x32_bf16(af[i], bfr[j], acc[i][j], 0,0,0);
  }
  #pragma unroll
  for (int i=0;i<4;i++)
    #pragma unroll
    for (int j=0;j<4;j++)
      #pragma unroll
      for (int r=0;r<4;r++){
        int row = m0 + wm*64 + i*16 + lg*4 + r;
        int col = wn*64 + j*16 + lr;
        int gcol = n0 + col;
        float v = acc[i][j][r];
        if (EPI == 0) stout(&C[(size_t)row*N + gcol], v);
        if (EPI == 1){ v = softplus_fast(v + bias[gcol]); stout(&C[(size_t)row*N + gcol], v); }
      }
}

// ---- x_proj split-K x4 GEMM (BK=32): chunk c covers K in [c*512, c*512+512) ----
__global__ __launch_bounds__(256) void k_gemm_xk(
    const bf16* __restrict__ A, const bf16* __restrict__ BT,
    float* __restrict__ C0, float* __restrict__ C1,
    float* __restrict__ C2, float* __restrict__ C3)
{
  __shared__ __align__(16) bf16 As[128*32];
  __shared__ __align__(16) bf16 Bs[128*32];
  int tid = threadIdx.x;
  int nwg = gridDim.x;
  int wg  = (blockIdx.x & 7) * (nwg >> 3) + (blockIdx.x >> 3);
  int chunk = wg >> 7;
  int bm = wg & 127;
  int m0 = bm << 7;
  int kbase = chunk << 9;
  int w = tid >> 6, l = tid & 63, lr = l & 15, lg = l >> 4;
  int wm = w >> 1, wn = w & 1;
  f32x4 acc[4][4] = {};
  int r0 = tid >> 2, c0 = (tid & 3) << 3;
  const bf16* Asrc = A  + (size_t)(m0 + r0) * 2048 + kbase + c0;
  const bf16* Bsrc = BT + (size_t)r0 * 2048 + kbase + c0;
  bf16* AsW = As + w*512;
  bf16* BsW = Bs + w*512;
  float* Cp = (chunk==0) ? C0 : (chunk==1) ? C1 : (chunk==2) ? C2 : C3;
  for (int kt = 0; kt < 512; kt += 32){
    __syncthreads();
    gload_lds16(Asrc + kt,                      AsW);
    gload_lds16(Asrc + (size_t)64*2048 + kt,    AsW + 2048);
    gload_lds16(Bsrc + kt,                      BsW);
    gload_lds16(Bsrc + (size_t)64*2048 + kt,    BsW + 2048);
    __syncthreads();
    bf16x8 af[4], bfr[4];
    #pragma unroll
    for (int i=0;i<4;i++) af[i]  = *(const bf16x8*)(As + (wm*64 + i*16 + lr)*32 + lg*8);
    #pragma unroll
    for (int j=0;j<4;j++) bfr[j] = *(const bf16x8*)(Bs + (wn*64 + j*16 + lr)*32 + lg*8);
    #pragma unroll
    for (int i=0;i<4;i++)
      #pragma unroll
      for (int j=0;j<4;j++)
        acc[i][j] = __builtin_amdgcn_mfma_f32_16x16x32_bf16(af[i], bfr[j], acc[i][j], 0,0,0);
  }
  #pragma unroll
  for (int i=0;i<4;i++)
    #pragma unroll
    for (int j=0;j<4;j++)
      #pragma unroll
      for (int r=0;r<4;r++){
        int row = m0 + wm*64 + i*16 + lg*4 + r;
        int gcol = wn*64 + j*16 + lr;
        Cp[(size_t)row*128 + gcol] = acc[i][j][r];
      }
}

// ---- x_proj fixup: xd = p0+p1+p2+p3 (in place into xd); dt = bf16(xd[:, :64]) ----
__global__ __launch_bounds__(256) void k_xproj_fix(
    float* __restrict__ xd, const float* __restrict__ p1,
    const float* __restrict__ p2, const float* __restrict__ p3,
    bf16* __restrict__ dt)
{
  int idx = blockIdx.x*256 + threadIdx.x;   // 16384*128
  int row = idx >> 7, col = idx & 127;
  float v = xd[idx] + p1[idx] + p2[idx] + p3[idx];
  xd[idx] = v;
  if (col < 64) dt[(row << 6) + col] = f2bf(v);
}

// ---- causal depthwise conv (DC=4) + SiLU, sliding-window vectorized ----
__global__ __launch_bounds__(256) void k_conv(
    const bf16* __restrict__ u, const float* __restrict__ cwT, const float* __restrict__ cb,
    bf16* __restrict__ uc)
{
  int tid = threadIdx.x;
  int d = tid << 3;
  int tok0 = blockIdx.x << 4;       // 1024 blocks x 16 tokens
  int n0 = tok0 & 511;              // position within batch
  float wk[4][8];
  #pragma unroll
  for (int k=0;k<4;k++){
    *(float4*)&wk[k][0] = *(const float4*)(cwT + k*2048 + d);
    *(float4*)&wk[k][4] = *(const float4*)(cwT + k*2048 + d + 4);
  }
  float cbv[8];
  *(float4*)&cbv[0] = *(const float4*)(cb + d);
  *(float4*)&cbv[4] = *(const float4*)(cb + d + 4);
  bf16x8 w0, w1, w2;
  if (n0 == 0){
    w0 = (bf16x8){0,0,0,0,0,0,0,0}; w1 = w0; w2 = w0;
  } else {
    w0 = *(const bf16x8*)(u + (size_t)(tok0-3)*2048 + d);
    w1 = *(const bf16x8*)(u + (size_t)(tok0-2)*2048 + d);
    w2 = *(const bf16x8*)(u + (size_t)(tok0-1)*2048 + d);
  }
  #pragma unroll 4
  for (int t=0; t<16; ++t){
    size_t tok = (size_t)(tok0 + t);
    bf16x8 cur = *(const bf16x8*)(u + tok*2048 + d);
    bf16x8 res;
    #pragma unroll
    for (int j=0;j<8;j++){
      float a = cbv[j]
              + wk[0][j]*bfs2f(w0[j]) + wk[1][j]*bfs2f(w1[j])
              + wk[2][j]*bfs2f(w2[j]) + wk[3][j]*bfs2f(cur[j]);
      res[j] = f2bfs(a * fast_sigmoid(a));
    }
    *(bf16x8*)(uc + tok*2048 + d) = res;
    w0 = w1; w1 = w2; w2 = cur;
  }
}

// ---- selective scan: wave-per-state-quad mapping, scalar B/C loads ----
__global__ __launch_bounds__(256) void k_scan(
    const bf16* __restrict__ delta, const bf16* __restrict__ uc, const bf16* __restrict__ g,
    const float* __restrict__ xd, const float* __restrict__ A_log,
    const float* __restrict__ Dp, float* __restrict__ ysum)
{
  __shared__ float red[4][64];
  int tid = threadIdx.x;
  int q = tid >> 6;          // wave id = state quad (uniform within wave)
  int l = tid & 63;          // d within the block's 64-d slab
  int b = blockIdx.x >> 5;
  int d = ((blockIdx.x & 31) << 6) + l;
  const float L2E = 1.44269504f;
  float4 t4 = *(const float4*)(A_log + (size_t)d*16 + q*4);
  float An0 = -__expf(t4.x)*L2E, An1 = -__expf(t4.y)*L2E,
        An2 = -__expf(t4.z)*L2E, An3 = -__expf(t4.w)*L2E;
  float Dd = (q == 0) ? Dp[d] : 0.0f;
  float h0=0.f,h1=0.f,h2=0.f,h3=0.f;
  float acc = 0.0f;
  unsigned o1 = (unsigned)b*1048576u + (unsigned)d;       // elem offset delta/uc/g
  unsigned o2 = (unsigned)__builtin_amdgcn_readfirstlane((unsigned)(b*16384 + 16 + q));
  const float4* __restrict__ x4 = (const float4*)xd;
  #pragma unroll 4
  for (int t=0; t<512; ++t){
    float dt = bf2f(delta[o1]);
    float ut = bf2f(uc[o1]);
    float gt = bf2f(g[o1]);
    float4 Bq = x4[o2];
    float4 Cq = x4[o2 + 4u];
    o1 += 2048u; o2 += 32u;
    float du = dt*ut;
    float y;
    float e0 = hw_exp2(dt*An0); h0 = h0*e0 + du*Bq.x; y  = h0*Cq.x;
    float e1 = hw_exp2(dt*An1); h1 = h1*e1 + du*Bq.y; y += h1*Cq.y;
    float e2 = hw_exp2(dt*An2); h2 = h2*e2 + du*Bq.z; y += h2*Cq.z;
    float e3 = hw_exp2(dt*An3); h3 = h3*e3 + du*Bq.w; y += h3*Cq.w;
    acc += (y + ut*Dd) * gt;
  }
  red[q][l] = acc;
  __syncthreads();
  if (q == 0)
    ysum[(size_t)b*2048 + d] = red[0][l] + red[1][l] + red[2][l] + red[3][l];
}

// ---- split-K pooled GEMM part 1 ----
__global__ __launch_bounds__(256) void k_poolgemm_part(
    const float* __restrict__ ysum, const float* __restrict__ Wo, float* __restrict__ partial)
{
  __shared__ float ys[32][64];
  int tid = threadIdx.x;
  int jb = blockIdx.x & 15;
  int kc = blockIdx.x >> 4;
  int j  = jb*64 + (tid & 63);
  int b0 = tid >> 6;
  #pragma unroll
  for (int i=0;i<8;i++){
    int e = tid + i*256;
    int bb = e >> 6, kk = e & 63;
    ys[bb][kk] = ysum[(size_t)bb*2048 + kc*64 + kk];
  }
  __syncthreads();
  float acc[8];
  #pragma unroll
  for (int p=0;p<8;p++) acc[p] = 0.f;
  #pragma unroll 4
  for (int kk=0;kk<64;kk++){
    float wv = Wo[(size_t)(kc*64 + kk)*1024 + j];
    #pragma unroll
    for (int p=0;p<8;p++) acc[p] += ys[b0*8 + p][kk] * wv;
  }
  #pragma unroll
  for (int p=0;p<8;p++)
    partial[((size_t)kc*32 + b0*8 + p)*1024 + j] = acc[p];
}

// ---- split-K pooled GEMM part 2 ----
__global__ __launch_bounds__(256) void k_pool_reduce(
    const float* __restrict__ partial, float* __restrict__ pooled)
{
  int idx = blockIdx.x*256 + threadIdx.x;    // 32768
  float s = 0.f;
  #pragma unroll 8
  for (int kc=0;kc<32;kc++) s += partial[(size_t)kc*32768 + idx];
  pooled[idx] = s * (1.0f/512.0f);
}

// ---- head: LN(1024) -> dot Wh + bh ----
__global__ __launch_bounds__(256) void k_head(
    const float* __restrict__ pooled, const float* __restrict__ g, const float* __restrict__ bb,
    const float* __restrict__ Wh, const float* __restrict__ bh, float* __restrict__ out)
{
  __shared__ float red[8];
  int b = blockIdx.x, tid = threadIdx.x;
  float v[4];
  #pragma unroll
  for (int q=0;q<4;q++) v[q] = pooled[(size_t)b*1024 + tid + q*256];
  float s1 = v[0]+v[1]+v[2]+v[3];
  float s2 = v[0]*v[0]+v[1]*v[1]+v[2]*v[2]+v[3]*v[3];
  #pragma unroll
  for (int o=32;o;o>>=1){ s1 += __shfl_down(s1,o,64); s2 += __shfl_down(s2,o,64); }
  int w = tid>>6, l = tid&63;
  if (l==0){ red[w]=s1; red[4+w]=s2; }
  __syncthreads();
  float mu  = (red[0]+red[1]+red[2]+red[3])*(1.0f/1024.0f);
  float var = (red[4]+red[5]+red[6]+red[7])*(1.0f/1024.0f) - mu*mu;
  float rs = rsqrtf(var + 1e-5f);
  float p = 0.f;
  #pragma unroll
  for (int q=0;q<4;q++){
    int jv = tid + q*256;
    p += ((v[q]-mu)*rs*g[jv] + bb[jv]) * Wh[jv];
  }
  #pragma unroll
  for (int o=32;o;o>>=1) p += __shfl_down(p,o,64);
  __syncthreads();
  if (l==0) red[w] = p;
  __syncthreads();
  if (tid==0) out[b] = red[0]+red[1]+red[2]+red[3] + bh[0];
}

extern "C" void kernel_launch(void* const* d_in, const int* in_sizes, int n_in,
                              void* d_out, int out_size, void* d_ws, size_t ws_size,
                              hipStream_t stream)
{
  const float* x     = (const float*)d_in[0];
  const float* ln1_g = (const float*)d_in[1];
  const float* ln1_b = (const float*)d_in[2];
  const float* Wp    = (const float*)d_in[3];
  const float* bp    = (const float*)d_in[4];
  const float* ln2_g = (const float*)d_in[5];
  const float* ln2_b = (const float*)d_in[6];
  const float* W_in  = (const float*)d_in[7];
  const float* conv_w= (const float*)d_in[8];
  const float* conv_b= (const float*)d_in[9];
  const float* W_x   = (const float*)d_in[10];
  const float* W_dt  = (const float*)d_in[11];
  const float* b_dt  = (const float*)d_in[12];
  const float* A_log = (const float*)d_in[13];
  const float* Dv    = (const float*)d_in[14];
  const float* W_out = (const float*)d_in[15];
  const float* ln3_g = (const float*)d_in[16];
  const float* ln3_b = (const float*)d_in[17];
  const float* Wh    = (const float*)d_in[18];
  const float* bh    = (const float*)d_in[19];

  // ---- workspace layout with liveness-based aliasing; peak ~234.8 MiB ----
  char* ws = (char*)d_ws;
  size_t o = 0;
  bf16*  u_delta = (bf16*)(ws + o); o += (size_t)NTOK*DI_*2;   // 64 MiB: u, then xpart2/3, then delta
  bf16*  zbuf    = (bf16*)(ws + o); o += (size_t)NTOK*DI_*2;   // 64 MiB: g = silu(z)
  bf16*  ucbuf   = (bf16*)(ws + o); o += (size_t)NTOK*DI_*2;   // 64 MiB: uc (persistent)
  char*  poolA   = (ws + o);        o += (size_t)NTOK*DM_*2;   // 32 MiB: h, later xd/dt/...
  bf16*  winT    = (bf16*)(ws + o); o += (size_t)2*DI_*DM_*2;  //  8 MiB: in_proj^T; later xpart1
  float* pe      = (float*)(ws + o); o += (size_t)NP_*DM_*4;   //  2 MiB
  bf16*  wxT     = (bf16*)(ws + o); o += (size_t)128*2048*2;   //  0.5 MiB (dedicated; no alias)
  bf16*  wdtT    = (bf16*)(ws + o); o += (size_t)2048*64*2;    //  0.25 MiB
  float* cwT     = (float*)(ws + o); o += (size_t)4*2048*4;    //  32 KiB
  bf16*  hbuf    = (bf16*)poolA;                 // phase-1
  float* xdbuf   = (float*)(poolA + 0);          // 8.0 MiB  [16384,128] f32
  bf16*  dtbuf   = (bf16*) (poolA + 8388608);    // 2.0 MiB  [16384,64]
  float* ysumbuf = (float*)(poolA + 11272192);   // 0.25 MiB [32,2048]
  float* pooledb = (float*)(poolA + 11534336);   // 0.13 MiB [32,1024]
  float* partial = (float*)(poolA + 12582912);   // 4.0 MiB  [32,32,1024]
  float* xpart1  = (float*)winT;                 // 8.0 MiB  (winT dead after gemm256)
  float* xpart2  = (float*)u_delta;              // 8.0 MiB  (u dead after conv)
  float* xpart3  = (float*)((char*)u_delta + 8388608); // 8.0 MiB

  // all weight preps + posemb in one kernel (saves 4 launches)
  k_prep_all      <<<3200, 256, 0, stream>>>(W_in, winT, W_x, wxT, W_dt, wdtT, pe, conv_w, cwT);
  k_patch         <<<1024, 256, 0, stream>>>(x, ln1_g, ln1_b, Wp, bp, ln2_g, ln2_b, pe, hbuf);
  // merged in_proj via 256^2 8-wave counted-vmcnt kernel
  k_gemm256       <<<1024, 512, 0, stream>>>(hbuf, winT, u_delta, zbuf, NTOK, 4096, 1024);
  // conv(u) -> uc   (hbuf + u dead from here)
  k_conv          <<<1024, 256, 0, stream>>>(u_delta, cwT, conv_b, ucbuf);
  // x_proj: split-K x4 (partials in dead winT + u_delta), then fixup emits xd + dt
  k_gemm_xk       <<<512,  256, 0, stream>>>(ucbuf, wxT, xdbuf, xpart1, xpart2, xpart3);
  k_xproj_fix     <<<8192, 256, 0, stream>>>(xdbuf, xpart1, xpart2, xpart3, dtbuf);
  // delta = softplus(dt @ W_dt + b_dt)  (overwrites u_delta; xparts dead)
  k_gemm_bt<1,bf16><<<2048,256, 0, stream>>>(dtbuf, wdtT, u_delta, nullptr, NTOK, 2048, 64, b_dt);
  // fused scan + D-skip + gate + token-sum (wave-per-q, scalar B/C loads)
  k_scan          <<<1024, 256, 0, stream>>>(u_delta, ucbuf, zbuf, xdbuf, A_log, Dv, ysumbuf);
  // pooled = (ysum/512) @ W_out : split-K over 512 blocks, then reduce
  k_poolgemm_part <<<512,  256, 0, stream>>>(ysumbuf, W_out, partial);
  k_pool_reduce   <<<128,  256, 0, stream>>>(partial, pooledb);
  k_head          <<<32,   256, 0, stream>>>(pooledb, ln3_g, ln3_b, Wh, bh, (float*)d_out);
  (void)in_sizes; (void)n_in; (void)out_size; (void)ws_size;
}